// Round 1
// baseline (847.591 us; speedup 1.0000x reference)
//
#include <hip/hip_runtime.h>
#include <hip/hip_bf16.h>

typedef unsigned short u16;
typedef unsigned int   u32;
typedef unsigned long long uptr;
typedef short bf16x8 __attribute__((ext_vector_type(8)));
typedef float f32x4  __attribute__((ext_vector_type(4)));

#define PIMG 9216           // 96*96 pixels per image
#define HH 96
#define WW 96
// 256/(512*sqrt(96)) = 0.5/sqrt(96)
#define SCALE 0.05103103630798288f

__device__ __forceinline__ u16 f2b(float f) {          // fp32 -> bf16 RNE
  u32 u = __float_as_uint(f);
  u += 0x7fffu + ((u >> 16) & 1u);
  return (u16)(u >> 16);
}
__device__ __forceinline__ float bl(u32 u) { return __uint_as_float(u << 16); }
__device__ __forceinline__ float bh(u32 u) { return __uint_as_float(u & 0xffff0000u); }

__device__ __forceinline__ void gl2lds16(const void* g, void* l) {
  __builtin_amdgcn_global_load_lds(
      (const __attribute__((address_space(1))) void*)(uptr)g,
      (__attribute__((address_space(3))) void*)(uptr)l, 16, 0, 0);
}

// ---------------------------------------------------------------------------
// fp32 [C][P] -> bf16 [P][C] transpose+convert (per batch in blockIdx.z)
// ---------------------------------------------------------------------------
__global__ void __launch_bounds__(256)
transpose_cvt(const float* __restrict__ src, u16* __restrict__ dst) {
  __shared__ float tile[64][33];
  const int tx = threadIdx.x, ty = threadIdx.y;      // (32,8)
  const int p0 = blockIdx.x * 32, c0 = blockIdx.y * 64;
  const float* s = src + (size_t)blockIdx.z * 1024 * PIMG;
  u16* d = dst + (size_t)blockIdx.z * PIMG * 1024;
#pragma unroll
  for (int i = 0; i < 8; ++i) {
    int c = ty + i * 8;
    tile[c][tx] = s[(size_t)(c0 + c) * PIMG + p0 + tx];
  }
  __syncthreads();
#pragma unroll
  for (int i = 0; i < 4; ++i) {
    int p = ty + i * 8;
    u32 lo = f2b(tile[2 * tx][p]);
    u32 hi = f2b(tile[2 * tx + 1][p]);
    *(u32*)(d + (size_t)(p0 + p) * 1024 + c0 + 2 * tx) = lo | (hi << 16);
  }
}

// fp32 -> bf16 pairwise convert (weights)
__global__ void __launch_bounds__(256)
cvt_pairs(const float* __restrict__ s, u16* __restrict__ d, int n2) {
  int i = blockIdx.x * blockDim.x + threadIdx.x;
  if (i < n2) {
    float2 v = ((const float2*)s)[i];
    ((u32*)d)[i] = (u32)f2b(v.x) | ((u32)f2b(v.y) << 16);
  }
}

__global__ void zero1k(u32* z) { z[threadIdx.x] = 0; }   // 256 thr -> 1KB zeros

// ---------------------------------------------------------------------------
// GEMM: C[p][o] = sum_c A[p][c] * B[o][c]   (A row-major [M][K], B [N][K])
// 128x128 tile, BK=64, 4 waves, 4x4 16x16x32 bf16 MFMA subtiles per wave.
// ---------------------------------------------------------------------------
template <int EPI>
__global__ void __launch_bounds__(256)
gemm_bf16(const u16* __restrict__ A, const u16* __restrict__ B, int K,
          u16* __restrict__ outb, int ldo,
          const float* __restrict__ bias0, const float* __restrict__ bias1,
          int split, float* __restrict__ outf, const float* __restrict__ xres) {
  __shared__ u16 lds[2 * 128 * 64];                  // 32 KB
  u16* Alds = lds;
  u16* Blds = lds + 128 * 64;

  const int tid = threadIdx.x;
  const int wave = tid >> 6, lane = tid & 63;
  const int quad = lane >> 4, col = lane & 15;
  const int wr = wave >> 1, wc = wave & 1;
  const int m0 = blockIdx.y * 128, n0 = blockIdx.x * 128;

  f32x4 acc[4][4] = {};

  int srow[4], skc[4];
#pragma unroll
  for (int i = 0; i < 4; ++i) {
    int c = i * 256 + tid;
    srow[i] = c >> 3;
    skc[i] = (c & 7) ^ (srow[i] & 7);                // swizzled source chunk
  }

  for (int k0 = 0; k0 < K; k0 += 64) {
    __syncthreads();
#pragma unroll
    for (int i = 0; i < 4; ++i)
      gl2lds16(A + (size_t)(m0 + srow[i]) * K + k0 + skc[i] * 8,
               Alds + (i * 256 + wave * 64) * 8);
#pragma unroll
    for (int i = 0; i < 4; ++i)
      gl2lds16(B + (size_t)(n0 + srow[i]) * K + k0 + skc[i] * 8,
               Blds + (i * 256 + wave * 64) * 8);
    __syncthreads();
#pragma unroll
    for (int ks = 0; ks < 2; ++ks) {
      bf16x8 af[4], bfr[4];
#pragma unroll
      for (int mt = 0; mt < 4; ++mt) {
        int row = wr * 64 + mt * 16 + col;
        int pos = (ks * 4 + quad) ^ (row & 7);
        af[mt] = *(const bf16x8*)(Alds + row * 64 + pos * 8);
      }
#pragma unroll
      for (int nt = 0; nt < 4; ++nt) {
        int row = wc * 64 + nt * 16 + col;
        int pos = (ks * 4 + quad) ^ (row & 7);
        bfr[nt] = *(const bf16x8*)(Blds + row * 64 + pos * 8);
      }
#pragma unroll
      for (int mt = 0; mt < 4; ++mt)
#pragma unroll
        for (int nt = 0; nt < 4; ++nt)
          acc[mt][nt] = __builtin_amdgcn_mfma_f32_16x16x32_bf16(
              af[mt], bfr[nt], acc[mt][nt], 0, 0, 0);
    }
  }

  if (EPI == 0) {
#pragma unroll
    for (int nt = 0; nt < 4; ++nt) {
      int n = n0 + wc * 64 + nt * 16 + col;
      float bv = (n < split) ? bias0[n] : bias1[n - split];
#pragma unroll
      for (int mt = 0; mt < 4; ++mt) {
        int mb = m0 + wr * 64 + mt * 16 + quad * 4;
#pragma unroll
        for (int r = 0; r < 4; ++r)
          outb[(size_t)(mb + r) * ldo + n] = f2b(acc[mt][nt][r] + bv);
      }
    }
  } else {
    int b = m0 / PIMG;                               // tile never crosses image
    int pb = m0 - b * PIMG + wr * 64;
    const float* xr = xres + (size_t)b * 1024 * PIMG;
    float* op = outf + (size_t)b * 1024 * PIMG;
#pragma unroll
    for (int nt = 0; nt < 4; ++nt) {
      int n = n0 + wc * 64 + nt * 16 + col;
      float bv = bias0[n];
#pragma unroll
      for (int mt = 0; mt < 4; ++mt) {
        int p = pb + mt * 16 + quad * 4;
        const float4 xv = *(const float4*)(xr + (size_t)n * PIMG + p);
        float4 o;
        o.x = acc[mt][nt][0] + bv + xv.x;
        o.y = acc[mt][nt][1] + bv + xv.y;
        o.z = acc[mt][nt][2] + bv + xv.z;
        o.w = acc[mt][nt][3] + bv + xv.w;
        *(float4*)(op + (size_t)n * PIMG + p) = o;
      }
    }
  }
}

// ---------------------------------------------------------------------------
// Correlation via MFMA. Block = 8x8 pixel patch (grid 12x12x4).
// A = theta[64 patch pixels][512], B = phi[16x16 window pixels][512];
// scores[m][n] -> (p, q) with q = (ny-py)*9 + (nx-px) when both in [0,8].
// OOB phi rows are staged from a zero page (score 0, matching the zero-pad
// reference; zeros still participate in softmax downstream).
// ---------------------------------------------------------------------------
__global__ void __launch_bounds__(256)
corr_mfma(const u16* __restrict__ theta, const u16* __restrict__ gphi,
          float* __restrict__ scores, const u16* __restrict__ zpage) {
  __shared__ u16 tlds[64 * 64];                      // 8 KB
  __shared__ u16 plds[256 * 64];                     // 32 KB
  const int tid = threadIdx.x;
  const int wave = tid >> 6, lane = tid & 63;
  const int quad = lane >> 4, col = lane & 15;
  const int h0 = blockIdx.y * 8, w0 = blockIdx.x * 8;
  const int pb = blockIdx.z * PIMG;

  const u16* tsrc[2];
#pragma unroll
  for (int i = 0; i < 2; ++i) {
    int u = i * 256 + tid;
    int row = u >> 3, c = u & 7;
    int p = pb + (h0 + (row >> 3)) * 96 + w0 + (row & 7);
    tsrc[i] = theta + (size_t)p * 512 + ((c ^ (row & 7)) * 8);
  }
  const u16* psrc[8];
#pragma unroll
  for (int i = 0; i < 8; ++i) {
    int u = i * 256 + tid;
    int row = u >> 3, c = u & 7;
    int hh = h0 - 4 + (row >> 4), w2 = w0 - 4 + (row & 15);
    const u16* s = ((unsigned)hh < 96u && (unsigned)w2 < 96u)
        ? gphi + (size_t)(pb + hh * 96 + w2) * 1024 + 512 : zpage;
    psrc[i] = s + ((c ^ (row & 7)) * 8);
  }

  f32x4 acc[4][4] = {};
  for (int k0 = 0; k0 < 512; k0 += 64) {
    __syncthreads();
#pragma unroll
    for (int i = 0; i < 2; ++i)
      gl2lds16(tsrc[i] + k0, tlds + (i * 256 + wave * 64) * 8);
#pragma unroll
    for (int i = 0; i < 8; ++i)
      gl2lds16(psrc[i] + k0, plds + (i * 256 + wave * 64) * 8);
    __syncthreads();
#pragma unroll
    for (int ks = 0; ks < 2; ++ks) {
      bf16x8 af[4], bfr[4];
#pragma unroll
      for (int mt = 0; mt < 4; ++mt) {
        int row = mt * 16 + col;
        int pos = (ks * 4 + quad) ^ (row & 7);
        af[mt] = *(const bf16x8*)(tlds + row * 64 + pos * 8);
      }
#pragma unroll
      for (int nt = 0; nt < 4; ++nt) {
        int row = (wave * 4 + nt) * 16 + col;
        int pos = (ks * 4 + quad) ^ (row & 7);
        bfr[nt] = *(const bf16x8*)(plds + row * 64 + pos * 8);
      }
#pragma unroll
      for (int mt = 0; mt < 4; ++mt)
#pragma unroll
        for (int nt = 0; nt < 4; ++nt)
          acc[mt][nt] = __builtin_amdgcn_mfma_f32_16x16x32_bf16(
              af[mt], bfr[nt], acc[mt][nt], 0, 0, 0);
    }
  }

#pragma unroll
  for (int nt = 0; nt < 4; ++nt) {
    int ny = wave * 4 + nt;                          // window row of this n
#pragma unroll
    for (int mt = 0; mt < 4; ++mt) {
#pragma unroll
      for (int r = 0; r < 4; ++r) {
        int m = mt * 16 + quad * 4 + r;
        int py = m >> 3, pxl = m & 7;
        int a = ny - py, b = col - pxl;
        if ((unsigned)a <= 8u && (unsigned)b <= 8u) {
          int p = pb + (h0 + py) * 96 + w0 + pxl;
          scores[(size_t)p * 81 + a * 9 + b] = acc[mt][nt][r] * SCALE;
        }
      }
    }
  }
}

// ---------------------------------------------------------------------------
// Softmax + assemble, patch-tiled. Block = 8x8 pixel patch.
// wl[64][81]: softmax weights (wave 0 computes serially, one pixel/lane).
// g patch (16x16 px) staged per 64-ch chunk into LDS pitch 72 u16 (+16B pad,
// pad slots fed from zero page to keep global_load_lds lane-ordering).
// Thread (m = tid>>2, sub = tid&3) accumulates 16 channels of pixel m.
// ---------------------------------------------------------------------------
__global__ void __launch_bounds__(256)
assemble2(const float* __restrict__ scores, const u16* __restrict__ gphi,
          u16* __restrict__ y, const u16* __restrict__ zpage) {
  __shared__ float wl[64 * 81];                      // 20736 B
  __shared__ u16 gl[256 * 72];                       // 36864 B
  const int tid = threadIdx.x;
  const int wave = tid >> 6;
  const int h0 = blockIdx.y * 8, w0 = blockIdx.x * 8;
  const int pb = blockIdx.z * PIMG;

  for (int idx = tid; idx < 5184; idx += 256) {
    int m = idx / 81, q = idx - m * 81;
    int p = pb + (h0 + (m >> 3)) * 96 + w0 + (m & 7);
    wl[idx] = scores[(size_t)p * 81 + q];
  }
  __syncthreads();
  if (tid < 64) {                                    // wave-0 softmax
    float* row = wl + tid * 81;
    float mx = row[0];
    for (int q = 1; q < 81; ++q) mx = fmaxf(mx, row[q]);
    float s = 0.f;
    for (int q = 0; q < 81; ++q) s += __expf(row[q] - mx);
    float inv = 1.0f / s;
    for (int q = 0; q < 81; ++q) row[q] = __expf(row[q] - mx) * inv;
  }

  // staging sources: 256 rows x 9 units (8 data + 1 pad) = 2304 units
  const u16* gsrc[9];
#pragma unroll
  for (int i = 0; i < 9; ++i) {
    int u = i * 256 + tid;
    int n = u / 9, ck = u - n * 9;
    int hh = h0 - 4 + (n >> 4), w2 = w0 - 4 + (n & 15);
    bool v = (ck < 8) && ((unsigned)hh < 96u) && ((unsigned)w2 < 96u);
    gsrc[i] = v ? gphi + (size_t)(pb + hh * 96 + w2) * 1024 + ck * 8 : zpage;
  }

  const int m = tid >> 2, sub = tid & 3;
  const int py = m >> 3, pxl = m & 7;
  const int nb = py * 16 + pxl;
  u16* yout = y + (size_t)(pb + (h0 + py) * 96 + w0 + pxl) * 512 + sub * 16;
  const float* wrow = wl + m * 81;

  for (int c0 = 0; c0 < 512; c0 += 64) {
    __syncthreads();                                 // also fences softmax
#pragma unroll
    for (int i = 0; i < 9; ++i)
      gl2lds16(gsrc[i] + c0, gl + (i * 256 + wave * 64) * 8);
    __syncthreads();
    float2 a2[8] = {};
    int q = 0;
    for (int a = 0; a < 9; ++a) {
      const u16* gra = gl + (nb + a * 16) * 72 + sub * 16;
#pragma unroll
      for (int b = 0; b < 9; ++b) {
        float wq = wrow[q]; ++q;
        const uint4 g0 = *(const uint4*)(gra + b * 72);
        const uint4 g1 = *(const uint4*)(gra + b * 72 + 8);
        a2[0].x += wq * bl(g0.x); a2[0].y += wq * bh(g0.x);
        a2[1].x += wq * bl(g0.y); a2[1].y += wq * bh(g0.y);
        a2[2].x += wq * bl(g0.z); a2[2].y += wq * bh(g0.z);
        a2[3].x += wq * bl(g0.w); a2[3].y += wq * bh(g0.w);
        a2[4].x += wq * bl(g1.x); a2[4].y += wq * bh(g1.x);
        a2[5].x += wq * bl(g1.y); a2[5].y += wq * bh(g1.y);
        a2[6].x += wq * bl(g1.z); a2[6].y += wq * bh(g1.z);
        a2[7].x += wq * bl(g1.w); a2[7].y += wq * bh(g1.w);
      }
    }
    uint4 o0, o1;
    o0.x = (u32)f2b(a2[0].x) | ((u32)f2b(a2[0].y) << 16);
    o0.y = (u32)f2b(a2[1].x) | ((u32)f2b(a2[1].y) << 16);
    o0.z = (u32)f2b(a2[2].x) | ((u32)f2b(a2[2].y) << 16);
    o0.w = (u32)f2b(a2[3].x) | ((u32)f2b(a2[3].y) << 16);
    o1.x = (u32)f2b(a2[4].x) | ((u32)f2b(a2[4].y) << 16);
    o1.y = (u32)f2b(a2[5].x) | ((u32)f2b(a2[5].y) << 16);
    o1.z = (u32)f2b(a2[6].x) | ((u32)f2b(a2[6].y) << 16);
    o1.w = (u32)f2b(a2[7].x) | ((u32)f2b(a2[7].y) << 16);
    *(uint4*)yout = o0;
    *(uint4*)(yout + 8) = o1;
    yout += 64;
  }
}

// ---------------------------------------------------------------------------
extern "C" void kernel_launch(void* const* d_in, const int* in_sizes, int n_in,
                              void* d_out, int out_size, void* d_ws,
                              size_t ws_size, hipStream_t stream) {
  const float* x    = (const float*)d_in[0];
  const float* xref = (const float*)d_in[1];
  const float* w_g  = (const float*)d_in[2];
  const float* b_g  = (const float*)d_in[3];
  const float* w_th = (const float*)d_in[4];
  const float* b_th = (const float*)d_in[5];
  const float* w_ph = (const float*)d_in[6];
  const float* b_ph = (const float*)d_in[7];
  const float* w_o  = (const float*)d_in[8];
  const float* b_o  = (const float*)d_in[9];

  char* ws = (char*)d_ws;
  // big holds x_ref^T (bf16), then x^T, then y — sequential lifetimes.
  u16*   big    = (u16*)(ws);                        // 75,497,472 B
  u16*   gphi   = (u16*)(ws + 75497472);             // 75,497,472 B
  u16*   theta  = (u16*)(ws + 150994944);            // 37,748,736 B
  float* scores = (float*)(ws + 188743680);          // 11,943,936 B
  u16*   wgp    = (u16*)(ws + 200687616);            //  2,097,152 B
  u16*   wth    = (u16*)(ws + 202784768);             //  1,048,576 B
  u16*   wout   = (u16*)(ws + 203833344);            //  1,048,576 B
  // zero page: carved inside `big` past y's 37.75MB live range (48MB offset);
  // zeroed after the last full overwrite of big (x transpose).
  u16*   zpage  = big + 24 * 1024 * 1024;            // 1 KB zeros

  // weights -> bf16 (w_g & w_phi stacked into one [1024][1024] B-operand)
  cvt_pairs<<<1024, 256, 0, stream>>>(w_g, wgp, 262144);
  cvt_pairs<<<1024, 256, 0, stream>>>(w_ph, wgp + 524288, 262144);
  cvt_pairs<<<1024, 256, 0, stream>>>(w_th, wth, 262144);
  cvt_pairs<<<1024, 256, 0, stream>>>(w_o, wout, 262144);

  dim3 tb(32, 8);
  // x_ref -> [p][c] bf16, then g|phi = xref^T x [w_g;w_phi]^T  (N=1024)
  transpose_cvt<<<dim3(288, 16, 4), tb, 0, stream>>>(xref, big);
  gemm_bf16<0><<<dim3(8, 288), 256, 0, stream>>>(big, wgp, 1024, gphi, 1024,
                                                 b_g, b_ph, 512, nullptr,
                                                 nullptr);
  // x -> [p][c] bf16 (reuses big), then theta (N=512)
  transpose_cvt<<<dim3(288, 16, 4), tb, 0, stream>>>(x, big);
  gemm_bf16<0><<<dim3(4, 288), 256, 0, stream>>>(big, wth, 1024, theta, 512,
                                                 b_th, b_th, 512, nullptr,
                                                 nullptr);

  zero1k<<<1, 256, 0, stream>>>((u32*)zpage);

  corr_mfma<<<dim3(12, 12, 4), 256, 0, stream>>>(theta, gphi, scores, zpage);
  assemble2<<<dim3(12, 12, 4), 256, 0, stream>>>(scores, gphi, big /* y */,
                                                 zpage);

  // out = x + y x w_out^T + b_out   (fp32, fused residual epilogue)
  gemm_bf16<1><<<dim3(8, 288), 256, 0, stream>>>(big, wout, 512, nullptr, 0,
                                                 b_o, b_o, 1024, (float*)d_out,
                                                 x);
}

// Round 2
// 756.459 us; speedup vs baseline: 1.1205x; 1.1205x over previous
//
#include <hip/hip_runtime.h>
#include <hip/hip_bf16.h>

typedef unsigned short u16;
typedef unsigned int   u32;
typedef unsigned long long uptr;
typedef short bf16x8 __attribute__((ext_vector_type(8)));
typedef float f32x4  __attribute__((ext_vector_type(4)));

#define PIMG 9216           // 96*96 pixels per image
#define HH 96
#define WW 96
// 256/(512*sqrt(96)) = 0.5/sqrt(96)
#define SCALE 0.05103103630798288f

__device__ __forceinline__ u16 f2b(float f) {          // fp32 -> bf16 RNE
  u32 u = __float_as_uint(f);
  u += 0x7fffu + ((u >> 16) & 1u);
  return (u16)(u >> 16);
}

__device__ __forceinline__ void gl2lds16(const void* g, void* l) {
  __builtin_amdgcn_global_load_lds(
      (const __attribute__((address_space(1))) void*)(uptr)g,
      (__attribute__((address_space(3))) void*)(uptr)l, 16, 0, 0);
}

// ---------------------------------------------------------------------------
// fp32 [C][P] -> bf16 [P][C] transpose+convert (per batch in blockIdx.z)
// ---------------------------------------------------------------------------
__global__ void __launch_bounds__(256)
transpose_cvt(const float* __restrict__ src, u16* __restrict__ dst) {
  __shared__ float tile[64][33];
  const int tx = threadIdx.x, ty = threadIdx.y;      // (32,8)
  const int p0 = blockIdx.x * 32, c0 = blockIdx.y * 64;
  const float* s = src + (size_t)blockIdx.z * 1024 * PIMG;
  u16* d = dst + (size_t)blockIdx.z * PIMG * 1024;
#pragma unroll
  for (int i = 0; i < 8; ++i) {
    int c = ty + i * 8;
    tile[c][tx] = s[(size_t)(c0 + c) * PIMG + p0 + tx];
  }
  __syncthreads();
#pragma unroll
  for (int i = 0; i < 4; ++i) {
    int p = ty + i * 8;
    u32 lo = f2b(tile[2 * tx][p]);
    u32 hi = f2b(tile[2 * tx + 1][p]);
    *(u32*)(d + (size_t)(p0 + p) * 1024 + c0 + 2 * tx) = lo | (hi << 16);
  }
}

// fp32 -> bf16 pairwise convert (weights)
__global__ void __launch_bounds__(256)
cvt_pairs(const float* __restrict__ s, u16* __restrict__ d, int n2) {
  int i = blockIdx.x * blockDim.x + threadIdx.x;
  if (i < n2) {
    float2 v = ((const float2*)s)[i];
    ((u32*)d)[i] = (u32)f2b(v.x) | ((u32)f2b(v.y) << 16);
  }
}

__global__ void zero1k(u32* z) { z[threadIdx.x] = 0; }   // 256 thr -> 1KB zeros

// ---------------------------------------------------------------------------
// GEMM: C[p][o] = sum_c A[p][c] * B[o][c]   (A row-major [M][K], B [N][K])
// 128x128 tile, BK=64, 4 waves, 4x4 16x16x32 bf16 MFMA subtiles per wave.
// ---------------------------------------------------------------------------
template <int EPI>
__global__ void __launch_bounds__(256)
gemm_bf16(const u16* __restrict__ A, const u16* __restrict__ B, int K,
          u16* __restrict__ outb, int ldo,
          const float* __restrict__ bias0, const float* __restrict__ bias1,
          int split, float* __restrict__ outf, const float* __restrict__ xres) {
  __shared__ u16 lds[2 * 128 * 64];                  // 32 KB
  u16* Alds = lds;
  u16* Blds = lds + 128 * 64;

  const int tid = threadIdx.x;
  const int wave = tid >> 6, lane = tid & 63;
  const int quad = lane >> 4, col = lane & 15;
  const int wr = wave >> 1, wc = wave & 1;
  const int m0 = blockIdx.y * 128, n0 = blockIdx.x * 128;

  f32x4 acc[4][4] = {};

  int srow[4], skc[4];
#pragma unroll
  for (int i = 0; i < 4; ++i) {
    int c = i * 256 + tid;
    srow[i] = c >> 3;
    skc[i] = (c & 7) ^ (srow[i] & 7);                // swizzled source chunk
  }

  for (int k0 = 0; k0 < K; k0 += 64) {
    __syncthreads();
#pragma unroll
    for (int i = 0; i < 4; ++i)
      gl2lds16(A + (size_t)(m0 + srow[i]) * K + k0 + skc[i] * 8,
               Alds + (i * 256 + wave * 64) * 8);
#pragma unroll
    for (int i = 0; i < 4; ++i)
      gl2lds16(B + (size_t)(n0 + srow[i]) * K + k0 + skc[i] * 8,
               Blds + (i * 256 + wave * 64) * 8);
    __syncthreads();
#pragma unroll
    for (int ks = 0; ks < 2; ++ks) {
      bf16x8 af[4], bfr[4];
#pragma unroll
      for (int mt = 0; mt < 4; ++mt) {
        int row = wr * 64 + mt * 16 + col;
        int pos = (ks * 4 + quad) ^ (row & 7);
        af[mt] = *(const bf16x8*)(Alds + row * 64 + pos * 8);
      }
#pragma unroll
      for (int nt = 0; nt < 4; ++nt) {
        int row = wc * 64 + nt * 16 + col;
        int pos = (ks * 4 + quad) ^ (row & 7);
        bfr[nt] = *(const bf16x8*)(Blds + row * 64 + pos * 8);
      }
#pragma unroll
      for (int mt = 0; mt < 4; ++mt)
#pragma unroll
        for (int nt = 0; nt < 4; ++nt)
          acc[mt][nt] = __builtin_amdgcn_mfma_f32_16x16x32_bf16(
              af[mt], bfr[nt], acc[mt][nt], 0, 0, 0);
    }
  }

  if (EPI == 0) {
#pragma unroll
    for (int nt = 0; nt < 4; ++nt) {
      int n = n0 + wc * 64 + nt * 16 + col;
      float bv = (n < split) ? bias0[n] : bias1[n - split];
#pragma unroll
      for (int mt = 0; mt < 4; ++mt) {
        int mb = m0 + wr * 64 + mt * 16 + quad * 4;
#pragma unroll
        for (int r = 0; r < 4; ++r)
          outb[(size_t)(mb + r) * ldo + n] = f2b(acc[mt][nt][r] + bv);
      }
    }
  } else {
    int b = m0 / PIMG;                               // tile never crosses image
    int pb = m0 - b * PIMG + wr * 64;
    const float* xr = xres + (size_t)b * 1024 * PIMG;
    float* op = outf + (size_t)b * 1024 * PIMG;
#pragma unroll
    for (int nt = 0; nt < 4; ++nt) {
      int n = n0 + wc * 64 + nt * 16 + col;
      float bv = bias0[n];
#pragma unroll
      for (int mt = 0; mt < 4; ++mt) {
        int p = pb + mt * 16 + quad * 4;
        const float4 xv = *(const float4*)(xr + (size_t)n * PIMG + p);
        float4 o;
        o.x = acc[mt][nt][0] + bv + xv.x;
        o.y = acc[mt][nt][1] + bv + xv.y;
        o.z = acc[mt][nt][2] + bv + xv.z;
        o.w = acc[mt][nt][3] + bv + xv.w;
        *(float4*)(op + (size_t)n * PIMG + p) = o;
      }
    }
  }
}

// ---------------------------------------------------------------------------
// Correlation via MFMA. Block = 8x8 pixel patch (grid 12x12x4).
// A = theta[64 patch pixels][512], B = phi[16x16 window pixels][512];
// scores[m][n] -> (p, q) with q = (ny-py)*9 + (nx-px) when both in [0,8].
// OOB phi rows are staged from a zero page (score 0, matching the zero-pad
// reference; zeros still participate in softmax downstream).
// ---------------------------------------------------------------------------
__global__ void __launch_bounds__(256)
corr_mfma(const u16* __restrict__ theta, const u16* __restrict__ gphi,
          float* __restrict__ scores, const u16* __restrict__ zpage) {
  __shared__ u16 tlds[64 * 64];                      // 8 KB
  __shared__ u16 plds[256 * 64];                     // 32 KB
  const int tid = threadIdx.x;
  const int wave = tid >> 6, lane = tid & 63;
  const int quad = lane >> 4, col = lane & 15;
  const int h0 = blockIdx.y * 8, w0 = blockIdx.x * 8;
  const int pb = blockIdx.z * PIMG;

  const u16* tsrc[2];
#pragma unroll
  for (int i = 0; i < 2; ++i) {
    int u = i * 256 + tid;
    int row = u >> 3, c = u & 7;
    int p = pb + (h0 + (row >> 3)) * 96 + w0 + (row & 7);
    tsrc[i] = theta + (size_t)p * 512 + ((c ^ (row & 7)) * 8);
  }
  const u16* psrc[8];
#pragma unroll
  for (int i = 0; i < 8; ++i) {
    int u = i * 256 + tid;
    int row = u >> 3, c = u & 7;
    int hh = h0 - 4 + (row >> 4), w2 = w0 - 4 + (row & 15);
    const u16* s = ((unsigned)hh < 96u && (unsigned)w2 < 96u)
        ? gphi + (size_t)(pb + hh * 96 + w2) * 1024 + 512 : zpage;
    psrc[i] = s + ((c ^ (row & 7)) * 8);
  }

  f32x4 acc[4][4] = {};
  for (int k0 = 0; k0 < 512; k0 += 64) {
    __syncthreads();
#pragma unroll
    for (int i = 0; i < 2; ++i)
      gl2lds16(tsrc[i] + k0, tlds + (i * 256 + wave * 64) * 8);
#pragma unroll
    for (int i = 0; i < 8; ++i)
      gl2lds16(psrc[i] + k0, plds + (i * 256 + wave * 64) * 8);
    __syncthreads();
#pragma unroll
    for (int ks = 0; ks < 2; ++ks) {
      bf16x8 af[4], bfr[4];
#pragma unroll
      for (int mt = 0; mt < 4; ++mt) {
        int row = mt * 16 + col;
        int pos = (ks * 4 + quad) ^ (row & 7);
        af[mt] = *(const bf16x8*)(tlds + row * 64 + pos * 8);
      }
#pragma unroll
      for (int nt = 0; nt < 4; ++nt) {
        int row = (wave * 4 + nt) * 16 + col;
        int pos = (ks * 4 + quad) ^ (row & 7);
        bfr[nt] = *(const bf16x8*)(plds + row * 64 + pos * 8);
      }
#pragma unroll
      for (int mt = 0; mt < 4; ++mt)
#pragma unroll
        for (int nt = 0; nt < 4; ++nt)
          acc[mt][nt] = __builtin_amdgcn_mfma_f32_16x16x32_bf16(
              af[mt], bfr[nt], acc[mt][nt], 0, 0, 0);
    }
  }

#pragma unroll
  for (int nt = 0; nt < 4; ++nt) {
    int ny = wave * 4 + nt;                          // window row of this n
#pragma unroll
    for (int mt = 0; mt < 4; ++mt) {
#pragma unroll
      for (int r = 0; r < 4; ++r) {
        int m = mt * 16 + quad * 4 + r;
        int py = m >> 3, pxl = m & 7;
        int a = ny - py, b = col - pxl;
        if ((unsigned)a <= 8u && (unsigned)b <= 8u) {
          int p = pb + (h0 + py) * 96 + w0 + pxl;
          scores[(size_t)p * 81 + a * 9 + b] = acc[mt][nt][r] * SCALE;
        }
      }
    }
  }
}

// ---------------------------------------------------------------------------
// Softmax + assemble via MFMA. Block = 8x8 pixel patch (grid 12x12x4).
// y[64 px][512 ch] = W[64 px][256 window px] x G[256 window px][512 ch].
// Phase 1: W (bf16, XOR-swizzled 16B chunks) built in 32KB LDS from scores;
//          softmax wave-parallel, 4 lanes per pixel row.
// Phase 2: per-wave A-fragments (its 16 W rows, all K=256) hoisted to regs;
//          LDS reused as G^T[64 ch][256 px] per 64-ch chunk, staged via
//          register 8x8 u16 transpose + swizzled ds_write_b128.
// Per chunk: 4mt x 4nt x 8k 16x16x32 MFMAs (wave = m-tile), fp32 accum.
// ---------------------------------------------------------------------------
__global__ void __launch_bounds__(256)
assemble3(const float* __restrict__ scores, const u16* __restrict__ gphi,
          u16* __restrict__ y) {
  __shared__ u16 smem[64 * 256];                     // 32 KB: W, then G^T
  const int tid = threadIdx.x;
  const int wave = tid >> 6, lane = tid & 63;
  const int quad = lane >> 4, col = lane & 15;
  const int h0 = blockIdx.y * 8, w0 = blockIdx.x * 8;
  const int pb = blockIdx.z * PIMG;

  // ---- zero W ----
  {
    uint4 z4 = make_uint4(0, 0, 0, 0);
#pragma unroll
    for (int i = 0; i < 8; ++i)
      *(uint4*)(smem + (tid * 8 + i) * 8) = z4;
  }
  __syncthreads();

  // ---- softmax (4 lanes per pixel row) + scatter into W ----
  {
    const int m = tid >> 2, part = tid & 3;
    const int py = m >> 3, px = m & 7;
    const float* srow = scores + (size_t)(pb + (h0 + py) * 96 + w0 + px) * 81;
    float s[21];
    float mx = -1e30f;
#pragma unroll
    for (int i = 0; i < 21; ++i) {
      int q = part + 4 * i;
      s[i] = (q < 81) ? srow[q] : -1e30f;
      mx = fmaxf(mx, s[i]);
    }
    mx = fmaxf(mx, __shfl_xor(mx, 1));
    mx = fmaxf(mx, __shfl_xor(mx, 2));
    float sum = 0.f;
#pragma unroll
    for (int i = 0; i < 21; ++i) {
      int q = part + 4 * i;
      float e = (q < 81) ? __expf(s[i] - mx) : 0.f;
      s[i] = e;
      sum += e;
    }
    sum += __shfl_xor(sum, 1);
    sum += __shfl_xor(sum, 2);
    float inv = 1.0f / sum;
#pragma unroll
    for (int i = 0; i < 21; ++i) {
      int q = part + 4 * i;
      if (q < 81) {
        int a = q / 9, b = q - a * 9;
        int n = (py + a) * 16 + px + b;               // window pixel index
        int addr = m * 256 + (((n >> 3) ^ (m & 7)) << 3) + (n & 7);
        smem[addr] = f2b(s[i] * inv);
      }
    }
  }
  __syncthreads();

  // ---- hoist this wave's A-fragments (W rows m = wave*16 + col) ----
  bf16x8 af[8];
  {
    int m = wave * 16 + col;
#pragma unroll
    for (int ks = 0; ks < 8; ++ks) {
      int c = (ks * 4 + quad) ^ (m & 7);
      af[ks] = *(const bf16x8*)(smem + m * 256 + c * 8);
    }
  }
  __syncthreads();                                   // smem now reusable

  // output row addresses for this lane's 4 acc rows
  int prow[4];
#pragma unroll
  for (int r = 0; r < 4; ++r) {
    int m = wave * 16 + quad * 4 + r;
    prow[r] = pb + (h0 + (m >> 3)) * 96 + w0 + (m & 7);
  }

  // staging: thread covers window px = gp*8+i (i<8), ch = cg*8 .. cg*8+7
  const int gp = tid & 31, cg = tid >> 5;
  const int hh = h0 - 4 + (gp >> 1);
  const int wb = w0 - 4 + (gp & 1) * 8;
  const bool vrow = (unsigned)hh < 96u;
  const u16* src[8];
  bool ok[8];
#pragma unroll
  for (int i = 0; i < 8; ++i) {
    int wwi = wb + i;
    ok[i] = vrow && ((unsigned)wwi < 96u);
    src[i] = gphi + (size_t)(pb + hh * 96 + wwi) * 1024 + cg * 8;
  }

  for (int c0 = 0; c0 < 512; c0 += 64) {
    uint4 v[8];
#pragma unroll
    for (int i = 0; i < 8; ++i) {
      uint4 t4 = make_uint4(0, 0, 0, 0);
      if (ok[i]) t4 = *(const uint4*)(src[i] + c0);
      v[i] = t4;
    }
    __syncthreads();                                 // prev chunk consumed
    // 8x8 u16 transpose; write row ch=cg*8+j, px gp*8..+7 (swizzled chunk)
#pragma unroll
    for (int j = 0; j < 8; ++j) {
      int sw = j >> 1;
      u32 x0 = ((const u32*)&v[0])[sw], x1 = ((const u32*)&v[1])[sw];
      u32 x2 = ((const u32*)&v[2])[sw], x3 = ((const u32*)&v[3])[sw];
      u32 x4 = ((const u32*)&v[4])[sw], x5 = ((const u32*)&v[5])[sw];
      u32 x6 = ((const u32*)&v[6])[sw], x7 = ((const u32*)&v[7])[sw];
      uint4 o;
      if (j & 1) {
        o.x = (x0 >> 16) | (x1 & 0xffff0000u);
        o.y = (x2 >> 16) | (x3 & 0xffff0000u);
        o.z = (x4 >> 16) | (x5 & 0xffff0000u);
        o.w = (x6 >> 16) | (x7 & 0xffff0000u);
      } else {
        o.x = (x0 & 0xffffu) | (x1 << 16);
        o.y = (x2 & 0xffffu) | (x3 << 16);
        o.z = (x4 & 0xffffu) | (x5 << 16);
        o.w = (x6 & 0xffffu) | (x7 << 16);
      }
      *(uint4*)(smem + (cg * 8 + j) * 256 + ((gp ^ j) << 3)) = o;
    }
    __syncthreads();

    f32x4 acc[4] = {};
#pragma unroll
    for (int ks = 0; ks < 8; ++ks) {
      bf16x8 bfr[4];
#pragma unroll
      for (int nt = 0; nt < 4; ++nt) {
        int ch = nt * 16 + col;
        int c = (ks * 4 + quad) ^ (ch & 7);
        bfr[nt] = *(const bf16x8*)(smem + ch * 256 + c * 8);
      }
#pragma unroll
      for (int nt = 0; nt < 4; ++nt)
        acc[nt] = __builtin_amdgcn_mfma_f32_16x16x32_bf16(af[ks], bfr[nt],
                                                          acc[nt], 0, 0, 0);
    }
#pragma unroll
    for (int nt = 0; nt < 4; ++nt) {
      int ch = c0 + nt * 16 + col;
#pragma unroll
      for (int r = 0; r < 4; ++r)
        y[(size_t)prow[r] * 512 + ch] = f2b(acc[nt][r]);
    }
  }
}

// ---------------------------------------------------------------------------
extern "C" void kernel_launch(void* const* d_in, const int* in_sizes, int n_in,
                              void* d_out, int out_size, void* d_ws,
                              size_t ws_size, hipStream_t stream) {
  const float* x    = (const float*)d_in[0];
  const float* xref = (const float*)d_in[1];
  const float* w_g  = (const float*)d_in[2];
  const float* b_g  = (const float*)d_in[3];
  const float* w_th = (const float*)d_in[4];
  const float* b_th = (const float*)d_in[5];
  const float* w_ph = (const float*)d_in[6];
  const float* b_ph = (const float*)d_in[7];
  const float* w_o  = (const float*)d_in[8];
  const float* b_o  = (const float*)d_in[9];

  char* ws = (char*)d_ws;
  // big holds x_ref^T (bf16), then x^T, then y — sequential lifetimes.
  u16*   big    = (u16*)(ws);                        // 75,497,472 B
  u16*   gphi   = (u16*)(ws + 75497472);             // 75,497,472 B
  u16*   theta  = (u16*)(ws + 150994944);            // 37,748,736 B
  float* scores = (float*)(ws + 188743680);          // 11,943,936 B
  u16*   wgp    = (u16*)(ws + 200687616);            //  2,097,152 B
  u16*   wth    = (u16*)(ws + 202784768);            //  1,048,576 B
  u16*   wout   = (u16*)(ws + 203833344);            //  1,048,576 B
  // zero page: carved inside `big` past y's 37.75MB live range (48MB offset);
  // zeroed after the last full overwrite of big (x transpose).
  u16*   zpage  = big + 24 * 1024 * 1024;            // 1 KB zeros

  // weights -> bf16 (w_g & w_phi stacked into one [1024][1024] B-operand)
  cvt_pairs<<<1024, 256, 0, stream>>>(w_g, wgp, 262144);
  cvt_pairs<<<1024, 256, 0, stream>>>(w_ph, wgp + 524288, 262144);
  cvt_pairs<<<1024, 256, 0, stream>>>(w_th, wth, 262144);
  cvt_pairs<<<1024, 256, 0, stream>>>(w_o, wout, 262144);

  dim3 tb(32, 8);
  // x_ref -> [p][c] bf16, then g|phi = xref^T x [w_g;w_phi]^T  (N=1024)
  transpose_cvt<<<dim3(288, 16, 4), tb, 0, stream>>>(xref, big);
  gemm_bf16<0><<<dim3(8, 288), 256, 0, stream>>>(big, wgp, 1024, gphi, 1024,
                                                 b_g, b_ph, 512, nullptr,
                                                 nullptr);
  // x -> [p][c] bf16 (reuses big), then theta (N=512)
  transpose_cvt<<<dim3(288, 16, 4), tb, 0, stream>>>(x, big);
  gemm_bf16<0><<<dim3(4, 288), 256, 0, stream>>>(big, wth, 1024, theta, 512,
                                                 b_th, b_th, 512, nullptr,
                                                 nullptr);

  zero1k<<<1, 256, 0, stream>>>((u32*)zpage);

  corr_mfma<<<dim3(12, 12, 4), 256, 0, stream>>>(theta, gphi, scores, zpage);
  assemble3<<<dim3(12, 12, 4), 256, 0, stream>>>(scores, gphi, big /* y */);

  // out = x + y x w_out^T + b_out   (fp32, fused residual epilogue)
  gemm_bf16<1><<<dim3(8, 288), 256, 0, stream>>>(big, wout, 512, nullptr, 0,
                                                 b_o, b_o, 1024, (float*)d_out,
                                                 x);
}

// Round 3
// 726.796 us; speedup vs baseline: 1.1662x; 1.0408x over previous
//
#include <hip/hip_runtime.h>
#include <hip/hip_bf16.h>

typedef unsigned short u16;
typedef unsigned int   u32;
typedef unsigned long long uptr;
typedef short bf16x8 __attribute__((ext_vector_type(8)));
typedef float f32x4  __attribute__((ext_vector_type(4)));

#define PIMG 9216           // 96*96 pixels per image
#define HH 96
#define WW 96
// 256/(512*sqrt(96)) = 0.5/sqrt(96)
#define SCALE 0.05103103630798288f

__device__ __forceinline__ u16 f2b(float f) {          // fp32 -> bf16 RNE
  u32 u = __float_as_uint(f);
  u += 0x7fffu + ((u >> 16) & 1u);
  return (u16)(u >> 16);
}

__device__ __forceinline__ void gl2lds16(const void* g, void* l) {
  __builtin_amdgcn_global_load_lds(
      (const __attribute__((address_space(1))) void*)(uptr)g,
      (__attribute__((address_space(3))) void*)(uptr)l, 16, 0, 0);
}

// ---------------------------------------------------------------------------
// fp32 [C][P] -> bf16 [P][C] transpose+convert (per batch in blockIdx.z)
// ---------------------------------------------------------------------------
__global__ void __launch_bounds__(256)
transpose_cvt(const float* __restrict__ src, u16* __restrict__ dst) {
  __shared__ float tile[64][33];
  const int tx = threadIdx.x, ty = threadIdx.y;      // (32,8)
  const int p0 = blockIdx.x * 32, c0 = blockIdx.y * 64;
  const float* s = src + (size_t)blockIdx.z * 1024 * PIMG;
  u16* d = dst + (size_t)blockIdx.z * PIMG * 1024;
#pragma unroll
  for (int i = 0; i < 8; ++i) {
    int c = ty + i * 8;
    tile[c][tx] = s[(size_t)(c0 + c) * PIMG + p0 + tx];
  }
  __syncthreads();
#pragma unroll
  for (int i = 0; i < 4; ++i) {
    int p = ty + i * 8;
    u32 lo = f2b(tile[2 * tx][p]);
    u32 hi = f2b(tile[2 * tx + 1][p]);
    *(u32*)(d + (size_t)(p0 + p) * 1024 + c0 + 2 * tx) = lo | (hi << 16);
  }
}

// fp32 -> bf16 pairwise convert (weights)
__global__ void __launch_bounds__(256)
cvt_pairs(const float* __restrict__ s, u16* __restrict__ d, int n2) {
  int i = blockIdx.x * blockDim.x + threadIdx.x;
  if (i < n2) {
    float2 v = ((const float2*)s)[i];
    ((u32*)d)[i] = (u32)f2b(v.x) | ((u32)f2b(v.y) << 16);
  }
}

__global__ void zero1k(u32* z) { z[threadIdx.x] = 0; }   // 256 thr -> 1KB zeros

// ---------------------------------------------------------------------------
// GEMM: C[p][o] = sum_c A[p][c] * B[o][c]   (A row-major [M][K], B [N][K])
// 128x128 tile, BK=64, 4 waves, 4x4 16x16x32 bf16 MFMA subtiles per wave.
// XCD-aware bijective swizzle (nwg % 8 == 0 for all our grids): each XCD
// owns a contiguous m-range, n fastest -> A-panel + B-stripe fit 4MB L2.
// ---------------------------------------------------------------------------
template <int EPI>
__global__ void __launch_bounds__(256)
gemm_bf16(const u16* __restrict__ A, const u16* __restrict__ B, int K,
          u16* __restrict__ outb, int ldo,
          const float* __restrict__ bias0, const float* __restrict__ bias1,
          int split, float* __restrict__ outf, const float* __restrict__ xres) {
  __shared__ u16 lds[2 * 128 * 64];                  // 32 KB
  u16* Alds = lds;
  u16* Blds = lds + 128 * 64;

  const int tid = threadIdx.x;
  const int wave = tid >> 6, lane = tid & 63;
  const int quad = lane >> 4, col = lane & 15;
  const int wr = wave >> 1, wc = wave & 1;

  const int nbx = gridDim.x;
  const int nwg = nbx * gridDim.y;
  const int id = blockIdx.x + nbx * blockIdx.y;
  const int nid = (id & 7) * (nwg >> 3) + (id >> 3); // bijective XCD swizzle
  const int m0 = (nid / nbx) * 128, n0 = (nid % nbx) * 128;

  f32x4 acc[4][4] = {};

  int srow[4], skc[4];
#pragma unroll
  for (int i = 0; i < 4; ++i) {
    int c = i * 256 + tid;
    srow[i] = c >> 3;
    skc[i] = (c & 7) ^ (srow[i] & 7);                // swizzled source chunk
  }

  for (int k0 = 0; k0 < K; k0 += 64) {
    __syncthreads();
#pragma unroll
    for (int i = 0; i < 4; ++i)
      gl2lds16(A + (size_t)(m0 + srow[i]) * K + k0 + skc[i] * 8,
               Alds + (i * 256 + wave * 64) * 8);
#pragma unroll
    for (int i = 0; i < 4; ++i)
      gl2lds16(B + (size_t)(n0 + srow[i]) * K + k0 + skc[i] * 8,
               Blds + (i * 256 + wave * 64) * 8);
    __syncthreads();
#pragma unroll
    for (int ks = 0; ks < 2; ++ks) {
      bf16x8 af[4], bfr[4];
#pragma unroll
      for (int mt = 0; mt < 4; ++mt) {
        int row = wr * 64 + mt * 16 + col;
        int pos = (ks * 4 + quad) ^ (row & 7);
        af[mt] = *(const bf16x8*)(Alds + row * 64 + pos * 8);
      }
#pragma unroll
      for (int nt = 0; nt < 4; ++nt) {
        int row = wc * 64 + nt * 16 + col;
        int pos = (ks * 4 + quad) ^ (row & 7);
        bfr[nt] = *(const bf16x8*)(Blds + row * 64 + pos * 8);
      }
#pragma unroll
      for (int mt = 0; mt < 4; ++mt)
#pragma unroll
        for (int nt = 0; nt < 4; ++nt)
          acc[mt][nt] = __builtin_amdgcn_mfma_f32_16x16x32_bf16(
              af[mt], bfr[nt], acc[mt][nt], 0, 0, 0);
    }
  }

  if (EPI == 0) {
#pragma unroll
    for (int nt = 0; nt < 4; ++nt) {
      int n = n0 + wc * 64 + nt * 16 + col;
      float bv = (n < split) ? bias0[n] : bias1[n - split];
#pragma unroll
      for (int mt = 0; mt < 4; ++mt) {
        int mb = m0 + wr * 64 + mt * 16 + quad * 4;
#pragma unroll
        for (int r = 0; r < 4; ++r)
          outb[(size_t)(mb + r) * ldo + n] = f2b(acc[mt][nt][r] + bv);
      }
    }
  } else {
    int b = m0 / PIMG;                               // tile never crosses image
    int pb = m0 - b * PIMG + wr * 64;
    const float* xr = xres + (size_t)b * 1024 * PIMG;
    float* op = outf + (size_t)b * 1024 * PIMG;
#pragma unroll
    for (int nt = 0; nt < 4; ++nt) {
      int n = n0 + wc * 64 + nt * 16 + col;
      float bv = bias0[n];
#pragma unroll
      for (int mt = 0; mt < 4; ++mt) {
        int p = pb + mt * 16 + quad * 4;
        const float4 xv = *(const float4*)(xr + (size_t)n * PIMG + p);
        float4 o;
        o.x = acc[mt][nt][0] + bv + xv.x;
        o.y = acc[mt][nt][1] + bv + xv.y;
        o.z = acc[mt][nt][2] + bv + xv.z;
        o.w = acc[mt][nt][3] + bv + xv.w;
        *(float4*)(op + (size_t)n * PIMG + p) = o;
      }
    }
  }
}

// ---------------------------------------------------------------------------
// Correlation via MFMA. Block = 8x8 pixel patch (grid 12x12x4).
// A = theta[64 patch pixels][512], B = phi[16x16 window pixels][512];
// scores[m][n] -> (p, q) with q = (ny-py)*9 + (nx-px) when both in [0,8].
// OOB phi rows are staged from a zero page (score 0, matching the zero-pad
// reference; zeros still participate in softmax downstream).
// ---------------------------------------------------------------------------
__global__ void __launch_bounds__(256)
corr_mfma(const u16* __restrict__ theta, const u16* __restrict__ gphi,
          float* __restrict__ scores, const u16* __restrict__ zpage) {
  __shared__ u16 tlds[64 * 64];                      // 8 KB
  __shared__ u16 plds[256 * 64];                     // 32 KB
  const int tid = threadIdx.x;
  const int wave = tid >> 6, lane = tid & 63;
  const int quad = lane >> 4, col = lane & 15;
  const int h0 = blockIdx.y * 8, w0 = blockIdx.x * 8;
  const int pb = blockIdx.z * PIMG;

  const u16* tsrc[2];
#pragma unroll
  for (int i = 0; i < 2; ++i) {
    int u = i * 256 + tid;
    int row = u >> 3, c = u & 7;
    int p = pb + (h0 + (row >> 3)) * 96 + w0 + (row & 7);
    tsrc[i] = theta + (size_t)p * 512 + ((c ^ (row & 7)) * 8);
  }
  const u16* psrc[8];
#pragma unroll
  for (int i = 0; i < 8; ++i) {
    int u = i * 256 + tid;
    int row = u >> 3, c = u & 7;
    int hh = h0 - 4 + (row >> 4), w2 = w0 - 4 + (row & 15);
    const u16* s = ((unsigned)hh < 96u && (unsigned)w2 < 96u)
        ? gphi + (size_t)(pb + hh * 96 + w2) * 1024 + 512 : zpage;
    psrc[i] = s + ((c ^ (row & 7)) * 8);
  }

  f32x4 acc[4][4] = {};
  for (int k0 = 0; k0 < 512; k0 += 64) {
    __syncthreads();
#pragma unroll
    for (int i = 0; i < 2; ++i)
      gl2lds16(tsrc[i] + k0, tlds + (i * 256 + wave * 64) * 8);
#pragma unroll
    for (int i = 0; i < 8; ++i)
      gl2lds16(psrc[i] + k0, plds + (i * 256 + wave * 64) * 8);
    __syncthreads();
#pragma unroll
    for (int ks = 0; ks < 2; ++ks) {
      bf16x8 af[4], bfr[4];
#pragma unroll
      for (int mt = 0; mt < 4; ++mt) {
        int row = mt * 16 + col;
        int pos = (ks * 4 + quad) ^ (row & 7);
        af[mt] = *(const bf16x8*)(tlds + row * 64 + pos * 8);
      }
#pragma unroll
      for (int nt = 0; nt < 4; ++nt) {
        int row = (wave * 4 + nt) * 16 + col;
        int pos = (ks * 4 + quad) ^ (row & 7);
        bfr[nt] = *(const bf16x8*)(plds + row * 64 + pos * 8);
      }
#pragma unroll
      for (int mt = 0; mt < 4; ++mt)
#pragma unroll
        for (int nt = 0; nt < 4; ++nt)
          acc[mt][nt] = __builtin_amdgcn_mfma_f32_16x16x32_bf16(
              af[mt], bfr[nt], acc[mt][nt], 0, 0, 0);
    }
  }

#pragma unroll
  for (int nt = 0; nt < 4; ++nt) {
    int ny = wave * 4 + nt;                          // window row of this n
#pragma unroll
    for (int mt = 0; mt < 4; ++mt) {
#pragma unroll
      for (int r = 0; r < 4; ++r) {
        int m = mt * 16 + quad * 4 + r;
        int py = m >> 3, pxl = m & 7;
        int a = ny - py, b = col - pxl;
        if ((unsigned)a <= 8u && (unsigned)b <= 8u) {
          int p = pb + (h0 + py) * 96 + w0 + pxl;
          scores[(size_t)p * 81 + a * 9 + b] = acc[mt][nt][r] * SCALE;
        }
      }
    }
  }
}

// ---------------------------------------------------------------------------
// Softmax + assemble via MFMA. Block = 8x8 pixel patch (grid 12x12x4).
// y[64 px][512 ch] = W[64 px][256 window px] x G[256 window px][512 ch].
// Phase 1: W (bf16, XOR-swizzled 16B chunks) built in 32KB LDS from scores;
//          softmax wave-parallel, 4 lanes per pixel row.
// Phase 2: per-wave A-fragments (its 16 W rows, all K=256) hoisted to regs;
//          LDS reused as G^T[64 ch][256 px] per 64-ch chunk, staged via
//          register 8x8 u16 transpose + swizzled ds_write_b128.
// Per chunk: 4mt x 4nt x 8k 16x16x32 MFMAs (wave = m-tile), fp32 accum.
// ---------------------------------------------------------------------------
__global__ void __launch_bounds__(256)
assemble3(const float* __restrict__ scores, const u16* __restrict__ gphi,
          u16* __restrict__ y) {
  __shared__ u16 smem[64 * 256];                     // 32 KB: W, then G^T
  const int tid = threadIdx.x;
  const int wave = tid >> 6, lane = tid & 63;
  const int quad = lane >> 4, col = lane & 15;
  const int h0 = blockIdx.y * 8, w0 = blockIdx.x * 8;
  const int pb = blockIdx.z * PIMG;

  // ---- zero W ----
  {
    uint4 z4 = make_uint4(0, 0, 0, 0);
#pragma unroll
    for (int i = 0; i < 8; ++i)
      *(uint4*)(smem + (tid * 8 + i) * 8) = z4;
  }
  __syncthreads();

  // ---- softmax (4 lanes per pixel row) + scatter into W ----
  {
    const int m = tid >> 2, part = tid & 3;
    const int py = m >> 3, px = m & 7;
    const float* srow = scores + (size_t)(pb + (h0 + py) * 96 + w0 + px) * 81;
    float s[21];
    float mx = -1e30f;
#pragma unroll
    for (int i = 0; i < 21; ++i) {
      int q = part + 4 * i;
      s[i] = (q < 81) ? srow[q] : -1e30f;
      mx = fmaxf(mx, s[i]);
    }
    mx = fmaxf(mx, __shfl_xor(mx, 1));
    mx = fmaxf(mx, __shfl_xor(mx, 2));
    float sum = 0.f;
#pragma unroll
    for (int i = 0; i < 21; ++i) {
      int q = part + 4 * i;
      float e = (q < 81) ? __expf(s[i] - mx) : 0.f;
      s[i] = e;
      sum += e;
    }
    sum += __shfl_xor(sum, 1);
    sum += __shfl_xor(sum, 2);
    float inv = 1.0f / sum;
#pragma unroll
    for (int i = 0; i < 21; ++i) {
      int q = part + 4 * i;
      if (q < 81) {
        int a = q / 9, b = q - a * 9;
        int n = (py + a) * 16 + px + b;               // window pixel index
        int addr = m * 256 + (((n >> 3) ^ (m & 7)) << 3) + (n & 7);
        smem[addr] = f2b(s[i] * inv);
      }
    }
  }
  __syncthreads();

  // ---- hoist this wave's A-fragments (W rows m = wave*16 + col) ----
  bf16x8 af[8];
  {
    int m = wave * 16 + col;
#pragma unroll
    for (int ks = 0; ks < 8; ++ks) {
      int c = (ks * 4 + quad) ^ (m & 7);
      af[ks] = *(const bf16x8*)(smem + m * 256 + c * 8);
    }
  }
  __syncthreads();                                   // smem now reusable

  // output row addresses for this lane's 4 acc rows
  int prow[4];
#pragma unroll
  for (int r = 0; r < 4; ++r) {
    int m = wave * 16 + quad * 4 + r;
    prow[r] = pb + (h0 + (m >> 3)) * 96 + w0 + (m & 7);
  }

  // staging: thread covers window px = gp*8+i (i<8), ch = cg*8 .. cg*8+7
  const int gp = tid & 31, cg = tid >> 5;
  const int hh = h0 - 4 + (gp >> 1);
  const int wb = w0 - 4 + (gp & 1) * 8;
  const bool vrow = (unsigned)hh < 96u;
  const u16* src[8];
  bool ok[8];
#pragma unroll
  for (int i = 0; i < 8; ++i) {
    int wwi = wb + i;
    ok[i] = vrow && ((unsigned)wwi < 96u);
    src[i] = gphi + (size_t)(pb + hh * 96 + wwi) * 1024 + cg * 8;
  }

  for (int c0 = 0; c0 < 512; c0 += 64) {
    uint4 v[8];
#pragma unroll
    for (int i = 0; i < 8; ++i) {
      uint4 t4 = make_uint4(0, 0, 0, 0);
      if (ok[i]) t4 = *(const uint4*)(src[i] + c0);
      v[i] = t4;
    }
    __syncthreads();                                 // prev chunk consumed
    // 8x8 u16 transpose; write row ch=cg*8+j, px gp*8..+7 (swizzled chunk)
#pragma unroll
    for (int j = 0; j < 8; ++j) {
      int sw = j >> 1;
      u32 x0 = ((const u32*)&v[0])[sw], x1 = ((const u32*)&v[1])[sw];
      u32 x2 = ((const u32*)&v[2])[sw], x3 = ((const u32*)&v[3])[sw];
      u32 x4 = ((const u32*)&v[4])[sw], x5 = ((const u32*)&v[5])[sw];
      u32 x6 = ((const u32*)&v[6])[sw], x7 = ((const u32*)&v[7])[sw];
      uint4 o;
      if (j & 1) {
        o.x = (x0 >> 16) | (x1 & 0xffff0000u);
        o.y = (x2 >> 16) | (x3 & 0xffff0000u);
        o.z = (x4 >> 16) | (x5 & 0xffff0000u);
        o.w = (x6 >> 16) | (x7 & 0xffff0000u);
      } else {
        o.x = (x0 & 0xffffu) | (x1 << 16);
        o.y = (x2 & 0xffffu) | (x3 << 16);
        o.z = (x4 & 0xffffu) | (x5 << 16);
        o.w = (x6 & 0xffffu) | (x7 << 16);
      }
      *(uint4*)(smem + (cg * 8 + j) * 256 + ((gp ^ j) << 3)) = o;
    }
    __syncthreads();

    f32x4 acc[4] = {};
#pragma unroll
    for (int ks = 0; ks < 8; ++ks) {
      bf16x8 bfr[4];
#pragma unroll
      for (int nt = 0; nt < 4; ++nt) {
        int ch = nt * 16 + col;
        int c = (ks * 4 + quad) ^ (ch & 7);
        bfr[nt] = *(const bf16x8*)(smem + ch * 256 + c * 8);
      }
#pragma unroll
      for (int nt = 0; nt < 4; ++nt)
        acc[nt] = __builtin_amdgcn_mfma_f32_16x16x32_bf16(af[ks], bfr[nt],
                                                          acc[nt], 0, 0, 0);
    }
#pragma unroll
    for (int nt = 0; nt < 4; ++nt) {
      int ch = c0 + nt * 16 + col;
#pragma unroll
      for (int r = 0; r < 4; ++r)
        y[(size_t)prow[r] * 512 + ch] = f2b(acc[nt][r]);
    }
  }
}

// ---------------------------------------------------------------------------
extern "C" void kernel_launch(void* const* d_in, const int* in_sizes, int n_in,
                              void* d_out, int out_size, void* d_ws,
                              size_t ws_size, hipStream_t stream) {
  const float* x    = (const float*)d_in[0];
  const float* xref = (const float*)d_in[1];
  const float* w_g  = (const float*)d_in[2];
  const float* b_g  = (const float*)d_in[3];
  const float* w_th = (const float*)d_in[4];
  const float* b_th = (const float*)d_in[5];
  const float* w_ph = (const float*)d_in[6];
  const float* b_ph = (const float*)d_in[7];
  const float* w_o  = (const float*)d_in[8];
  const float* b_o  = (const float*)d_in[9];

  char* ws = (char*)d_ws;
  // big holds x_ref^T (bf16), then x^T, then y — sequential lifetimes.
  u16*   big    = (u16*)(ws);                        // 75,497,472 B
  u16*   gphi   = (u16*)(ws + 75497472);             // 75,497,472 B
  u16*   theta  = (u16*)(ws + 150994944);            // 37,748,736 B
  float* scores = (float*)(ws + 188743680);          // 11,943,936 B
  u16*   wgp    = (u16*)(ws + 200687616);            //  2,097,152 B
  u16*   wth    = (u16*)(ws + 202784768);            //  1,048,576 B
  u16*   wout   = (u16*)(ws + 203833344);            //  1,048,576 B
  // zero page: carved inside `big` past y's 37.75MB live range (48MB offset);
  // zeroed after the last full overwrite of big (x transpose).
  u16*   zpage  = big + 24 * 1024 * 1024;            // 1 KB zeros

  // weights -> bf16 (w_g & w_phi stacked into one [1024][1024] B-operand)
  cvt_pairs<<<1024, 256, 0, stream>>>(w_g, wgp, 262144);
  cvt_pairs<<<1024, 256, 0, stream>>>(w_ph, wgp + 524288, 262144);
  cvt_pairs<<<1024, 256, 0, stream>>>(w_th, wth, 262144);
  cvt_pairs<<<1024, 256, 0, stream>>>(w_o, wout, 262144);

  dim3 tb(32, 8);
  // x_ref -> [p][c] bf16, then g|phi = xref^T x [w_g;w_phi]^T  (N=1024)
  transpose_cvt<<<dim3(288, 16, 4), tb, 0, stream>>>(xref, big);
  gemm_bf16<0><<<dim3(8, 288), 256, 0, stream>>>(big, wgp, 1024, gphi, 1024,
                                                 b_g, b_ph, 512, nullptr,
                                                 nullptr);
  // x -> [p][c] bf16 (reuses big), then theta (N=512)
  transpose_cvt<<<dim3(288, 16, 4), tb, 0, stream>>>(x, big);
  gemm_bf16<0><<<dim3(4, 288), 256, 0, stream>>>(big, wth, 1024, theta, 512,
                                                 b_th, b_th, 512, nullptr,
                                                 nullptr);

  zero1k<<<1, 256, 0, stream>>>((u32*)zpage);

  corr_mfma<<<dim3(12, 12, 4), 256, 0, stream>>>(theta, gphi, scores, zpage);
  assemble3<<<dim3(12, 12, 4), 256, 0, stream>>>(scores, gphi, big /* y */);

  // out = x + y x w_out^T + b_out   (fp32, fused residual epilogue)
  gemm_bf16<1><<<dim3(8, 288), 256, 0, stream>>>(big, wout, 512, nullptr, 0,
                                                 b_o, b_o, 1024, (float*)d_out,
                                                 x);
}

// Round 4
// 698.824 us; speedup vs baseline: 1.2129x; 1.0400x over previous
//
#include <hip/hip_runtime.h>
#include <hip/hip_bf16.h>

typedef unsigned short u16;
typedef unsigned int   u32;
typedef unsigned long long uptr;
typedef short bf16x8 __attribute__((ext_vector_type(8)));
typedef float f32x4  __attribute__((ext_vector_type(4)));

#define PIMG 9216           // 96*96 pixels per image
#define HH 96
#define WW 96
// 256/(512*sqrt(96)) = 0.5/sqrt(96)
#define SCALE 0.05103103630798288f

__device__ __forceinline__ u16 f2b(float f) {          // fp32 -> bf16 RNE
  u32 u = __float_as_uint(f);
  u += 0x7fffu + ((u >> 16) & 1u);
  return (u16)(u >> 16);
}

__device__ __forceinline__ void gl2lds16(const void* g, void* l) {
  __builtin_amdgcn_global_load_lds(
      (const __attribute__((address_space(1))) void*)(uptr)g,
      (__attribute__((address_space(3))) void*)(uptr)l, 16, 0, 0);
}

// ---------------------------------------------------------------------------
// fp32 [C][P] -> bf16 [P][C] transpose+convert (per batch in blockIdx.z)
// ---------------------------------------------------------------------------
__global__ void __launch_bounds__(256)
transpose_cvt(const float* __restrict__ src, u16* __restrict__ dst) {
  __shared__ float tile[64][33];
  const int tx = threadIdx.x, ty = threadIdx.y;      // (32,8)
  const int p0 = blockIdx.x * 32, c0 = blockIdx.y * 64;
  const float* s = src + (size_t)blockIdx.z * 1024 * PIMG;
  u16* d = dst + (size_t)blockIdx.z * PIMG * 1024;
#pragma unroll
  for (int i = 0; i < 8; ++i) {
    int c = ty + i * 8;
    tile[c][tx] = s[(size_t)(c0 + c) * PIMG + p0 + tx];
  }
  __syncthreads();
#pragma unroll
  for (int i = 0; i < 4; ++i) {
    int p = ty + i * 8;
    u32 lo = f2b(tile[2 * tx][p]);
    u32 hi = f2b(tile[2 * tx + 1][p]);
    *(u32*)(d + (size_t)(p0 + p) * 1024 + c0 + 2 * tx) = lo | (hi << 16);
  }
}

// fp32 -> bf16 pairwise convert (weights)
__global__ void __launch_bounds__(256)
cvt_pairs(const float* __restrict__ s, u16* __restrict__ d, int n2) {
  int i = blockIdx.x * blockDim.x + threadIdx.x;
  if (i < n2) {
    float2 v = ((const float2*)s)[i];
    ((u32*)d)[i] = (u32)f2b(v.x) | ((u32)f2b(v.y) << 16);
  }
}

__global__ void zero1k(u32* z) { z[threadIdx.x] = 0; }   // 256 thr -> 1KB zeros

// ---------------------------------------------------------------------------
// GEMM: C[p][o] = sum_c A[p][c] * B[o][c]   (A row-major [M][K], B [N][K])
// 256x128 tile, BK=64, 8 waves (2Mx4N), tri-buffered LDS, counted vmcnt(6),
// raw s_barrier (ONE per K-step), phased MFMA clusters with setprio.
// Pipeline: while computing step t, steps t+1 and t+2 loads are in flight.
//   RAW: own vmcnt + barrier (FIFO: oldest 6 = step t's loads).
//   WAR: step t+3 issues happen after barrier(t+1), which each wave passes
//        only after consuming its step-t ds_reads.
// XCD-aware bijective swizzle (nwg % 8 == 0 for all our grids).
// ---------------------------------------------------------------------------
#define BUFSZ (256 * 64 + 128 * 64)                  // u16 per buffer (48 KB)

template <int EPI>
__global__ void __launch_bounds__(512)
gemm256(const u16* __restrict__ A, const u16* __restrict__ B, int K,
        u16* __restrict__ outb, int ldo,
        const float* __restrict__ bias0, const float* __restrict__ bias1,
        int split, float* __restrict__ outf, const float* __restrict__ xres) {
  __shared__ __attribute__((aligned(16))) u16 lds[3 * BUFSZ];   // 144 KiB

  const int tid = threadIdx.x;
  const int wave = tid >> 6, lane = tid & 63;
  const int quad = lane >> 4, col = lane & 15;
  const int wr = wave >> 2, wc = wave & 3;           // 2 m-halves x 4 n-quads

  const int nbx = gridDim.x;
  const int nwg = nbx * gridDim.y;
  const int id = blockIdx.x + nbx * blockIdx.y;
  const int nid = (id & 7) * (nwg >> 3) + (id >> 3); // bijective XCD swizzle
  const int m0 = (nid / nbx) * 256, n0 = (nid % nbx) * 128;

  f32x4 acc[8][2] = {};

  // staging thread->unit maps (unit = 16B chunk), XOR-swizzled chunk in row
  int arow[4], akc[4];
#pragma unroll
  for (int i = 0; i < 4; ++i) {
    int u = i * 512 + tid;
    arow[i] = u >> 3;
    akc[i] = (u & 7) ^ (arow[i] & 7);
  }
  int brow[2], bkc[2];
#pragma unroll
  for (int i = 0; i < 2; ++i) {
    int u = i * 512 + tid;
    brow[i] = u >> 3;
    bkc[i] = (u & 7) ^ (brow[i] & 7);
  }

  const int NT = K >> 6;

#define STAGE_A(t, i)                                                      \
  gl2lds16(A + (size_t)(m0 + arow[i]) * K + (t) * 64 + akc[i] * 8,         \
           lds + ((t) % 3) * BUFSZ + ((i) * 512 + wave * 64) * 8)
#define STAGE_B(t, i)                                                      \
  gl2lds16(B + (size_t)(n0 + brow[i]) * K + (t) * 64 + bkc[i] * 8,         \
           lds + ((t) % 3) * BUFSZ + 256 * 64 + ((i) * 512 + wave * 64) * 8)

  // prologue: steps 0 and 1 in flight (12 loads/thread-wave)
  STAGE_A(0, 0); STAGE_A(0, 1); STAGE_A(0, 2); STAGE_A(0, 3);
  STAGE_B(0, 0); STAGE_B(0, 1);
  if (NT > 1) {
    STAGE_A(1, 0); STAGE_A(1, 1); STAGE_A(1, 2); STAGE_A(1, 3);
    STAGE_B(1, 0); STAGE_B(1, 1);
  }

  for (int t = 0; t < NT; ++t) {
    if (t + 1 < NT)
      asm volatile("s_waitcnt vmcnt(6)" ::: "memory");
    else
      asm volatile("s_waitcnt vmcnt(0)" ::: "memory");
    asm volatile("s_barrier" ::: "memory");

    const u16* bufA = lds + (t % 3) * BUFSZ;
    const u16* bufB = bufA + 256 * 64;
    const bool pf = (t + 2 < NT);

    bf16x8 bfr[2][2];
#pragma unroll
    for (int nt = 0; nt < 2; ++nt)
#pragma unroll
      for (int ks = 0; ks < 2; ++ks) {
        int row = wc * 32 + nt * 16 + col;
        int pos = (ks * 4 + quad) ^ (row & 7);
        bfr[nt][ks] = *(const bf16x8*)(bufB + row * 64 + pos * 8);
      }

#pragma unroll
    for (int q = 0; q < 4; ++q) {
      bf16x8 af[2][2];
#pragma unroll
      for (int mi = 0; mi < 2; ++mi)
#pragma unroll
        for (int ks = 0; ks < 2; ++ks) {
          int row = wr * 128 + (q * 2 + mi) * 16 + col;
          int pos = (ks * 4 + quad) ^ (row & 7);
          af[mi][ks] = *(const bf16x8*)(bufA + row * 64 + pos * 8);
        }
      if (pf) {
        if (q == 0) { STAGE_A(t + 2, 0); STAGE_A(t + 2, 1); }
        else if (q == 1) { STAGE_A(t + 2, 2); STAGE_A(t + 2, 3); }
        else if (q == 2) { STAGE_B(t + 2, 0); }
        else { STAGE_B(t + 2, 1); }
      }
      __builtin_amdgcn_s_setprio(1);
#pragma unroll
      for (int mi = 0; mi < 2; ++mi)
#pragma unroll
        for (int nt = 0; nt < 2; ++nt)
#pragma unroll
          for (int ks = 0; ks < 2; ++ks)
            acc[q * 2 + mi][nt] = __builtin_amdgcn_mfma_f32_16x16x32_bf16(
                af[mi][ks], bfr[nt][ks], acc[q * 2 + mi][nt], 0, 0, 0);
      __builtin_amdgcn_s_setprio(0);
    }
  }
#undef STAGE_A
#undef STAGE_B

  if (EPI == 0) {
#pragma unroll
    for (int nt = 0; nt < 2; ++nt) {
      int n = n0 + wc * 32 + nt * 16 + col;
      float bv = (n < split) ? bias0[n] : bias1[n - split];
#pragma unroll
      for (int mt = 0; mt < 8; ++mt) {
        int mb = m0 + wr * 128 + mt * 16 + quad * 4;
#pragma unroll
        for (int r = 0; r < 4; ++r)
          outb[(size_t)(mb + r) * ldo + n] = f2b(acc[mt][nt][r] + bv);
      }
    }
  } else {
    int b = m0 / PIMG;                               // tile never crosses image
    int pb = m0 - b * PIMG + wr * 128;
    const float* xr = xres + (size_t)b * 1024 * PIMG;
    float* op = outf + (size_t)b * 1024 * PIMG;
#pragma unroll
    for (int nt = 0; nt < 2; ++nt) {
      int n = n0 + wc * 32 + nt * 16 + col;
      float bv = bias0[n];
#pragma unroll
      for (int mt = 0; mt < 8; ++mt) {
        int p = pb + mt * 16 + quad * 4;
        const float4 xv = *(const float4*)(xr + (size_t)n * PIMG + p);
        float4 o;
        o.x = acc[mt][nt][0] + bv + xv.x;
        o.y = acc[mt][nt][1] + bv + xv.y;
        o.z = acc[mt][nt][2] + bv + xv.z;
        o.w = acc[mt][nt][3] + bv + xv.w;
        *(float4*)(op + (size_t)n * PIMG + p) = o;
      }
    }
  }
}

// ---------------------------------------------------------------------------
// Correlation via MFMA. Block = 8x8 pixel patch (grid 12x12x4).
// A = theta[64 patch pixels][512], B = phi[16x16 window pixels][512];
// scores[m][n] -> (p, q) with q = (ny-py)*9 + (nx-px) when both in [0,8].
// OOB phi rows are staged from a zero page (score 0, matching the zero-pad
// reference; zeros still participate in softmax downstream).
// ---------------------------------------------------------------------------
__global__ void __launch_bounds__(256)
corr_mfma(const u16* __restrict__ theta, const u16* __restrict__ gphi,
          float* __restrict__ scores, const u16* __restrict__ zpage) {
  __shared__ u16 tlds[64 * 64];                      // 8 KB
  __shared__ u16 plds[256 * 64];                     // 32 KB
  const int tid = threadIdx.x;
  const int wave = tid >> 6, lane = tid & 63;
  const int quad = lane >> 4, col = lane & 15;
  const int h0 = blockIdx.y * 8, w0 = blockIdx.x * 8;
  const int pb = blockIdx.z * PIMG;

  const u16* tsrc[2];
#pragma unroll
  for (int i = 0; i < 2; ++i) {
    int u = i * 256 + tid;
    int row = u >> 3, c = u & 7;
    int p = pb + (h0 + (row >> 3)) * 96 + w0 + (row & 7);
    tsrc[i] = theta + (size_t)p * 512 + ((c ^ (row & 7)) * 8);
  }
  const u16* psrc[8];
#pragma unroll
  for (int i = 0; i < 8; ++i) {
    int u = i * 256 + tid;
    int row = u >> 3, c = u & 7;
    int hh = h0 - 4 + (row >> 4), w2 = w0 - 4 + (row & 15);
    const u16* s = ((unsigned)hh < 96u && (unsigned)w2 < 96u)
        ? gphi + (size_t)(pb + hh * 96 + w2) * 1024 + 512 : zpage;
    psrc[i] = s + ((c ^ (row & 7)) * 8);
  }

  f32x4 acc[4][4] = {};
  for (int k0 = 0; k0 < 512; k0 += 64) {
    __syncthreads();
#pragma unroll
    for (int i = 0; i < 2; ++i)
      gl2lds16(tsrc[i] + k0, tlds + (i * 256 + wave * 64) * 8);
#pragma unroll
    for (int i = 0; i < 8; ++i)
      gl2lds16(psrc[i] + k0, plds + (i * 256 + wave * 64) * 8);
    __syncthreads();
#pragma unroll
    for (int ks = 0; ks < 2; ++ks) {
      bf16x8 af[4], bfr[4];
#pragma unroll
      for (int mt = 0; mt < 4; ++mt) {
        int row = mt * 16 + col;
        int pos = (ks * 4 + quad) ^ (row & 7);
        af[mt] = *(const bf16x8*)(tlds + row * 64 + pos * 8);
      }
#pragma unroll
      for (int nt = 0; nt < 4; ++nt) {
        int row = (wave * 4 + nt) * 16 + col;
        int pos = (ks * 4 + quad) ^ (row & 7);
        bfr[nt] = *(const bf16x8*)(plds + row * 64 + pos * 8);
      }
#pragma unroll
      for (int mt = 0; mt < 4; ++mt)
#pragma unroll
        for (int nt = 0; nt < 4; ++nt)
          acc[mt][nt] = __builtin_amdgcn_mfma_f32_16x16x32_bf16(
              af[mt], bfr[nt], acc[mt][nt], 0, 0, 0);
    }
  }

#pragma unroll
  for (int nt = 0; nt < 4; ++nt) {
    int ny = wave * 4 + nt;                          // window row of this n
#pragma unroll
    for (int mt = 0; mt < 4; ++mt) {
#pragma unroll
      for (int r = 0; r < 4; ++r) {
        int m = mt * 16 + quad * 4 + r;
        int py = m >> 3, pxl = m & 7;
        int a = ny - py, b = col - pxl;
        if ((unsigned)a <= 8u && (unsigned)b <= 8u) {
          int p = pb + (h0 + py) * 96 + w0 + pxl;
          scores[(size_t)p * 81 + a * 9 + b] = acc[mt][nt][r] * SCALE;
        }
      }
    }
  }
}

// ---------------------------------------------------------------------------
// Softmax + assemble via MFMA. Block = 8x8 pixel patch (grid 12x12x4).
// y[64 px][512 ch] = W[64 px][256 window px] x G[256 window px][512 ch].
// ---------------------------------------------------------------------------
__global__ void __launch_bounds__(256)
assemble3(const float* __restrict__ scores, const u16* __restrict__ gphi,
          u16* __restrict__ y) {
  __shared__ u16 smem[64 * 256];                     // 32 KB: W, then G^T
  const int tid = threadIdx.x;
  const int wave = tid >> 6, lane = tid & 63;
  const int quad = lane >> 4, col = lane & 15;
  const int h0 = blockIdx.y * 8, w0 = blockIdx.x * 8;
  const int pb = blockIdx.z * PIMG;

  // ---- zero W ----
  {
    uint4 z4 = make_uint4(0, 0, 0, 0);
#pragma unroll
    for (int i = 0; i < 8; ++i)
      *(uint4*)(smem + (tid * 8 + i) * 8) = z4;
  }
  __syncthreads();

  // ---- softmax (4 lanes per pixel row) + scatter into W ----
  {
    const int m = tid >> 2, part = tid & 3;
    const int py = m >> 3, px = m & 7;
    const float* srow = scores + (size_t)(pb + (h0 + py) * 96 + w0 + px) * 81;
    float s[21];
    float mx = -1e30f;
#pragma unroll
    for (int i = 0; i < 21; ++i) {
      int q = part + 4 * i;
      s[i] = (q < 81) ? srow[q] : -1e30f;
      mx = fmaxf(mx, s[i]);
    }
    mx = fmaxf(mx, __shfl_xor(mx, 1));
    mx = fmaxf(mx, __shfl_xor(mx, 2));
    float sum = 0.f;
#pragma unroll
    for (int i = 0; i < 21; ++i) {
      int q = part + 4 * i;
      float e = (q < 81) ? __expf(s[i] - mx) : 0.f;
      s[i] = e;
      sum += e;
    }
    sum += __shfl_xor(sum, 1);
    sum += __shfl_xor(sum, 2);
    float inv = 1.0f / sum;
#pragma unroll
    for (int i = 0; i < 21; ++i) {
      int q = part + 4 * i;
      if (q < 81) {
        int a = q / 9, b = q - a * 9;
        int n = (py + a) * 16 + px + b;               // window pixel index
        int addr = m * 256 + (((n >> 3) ^ (m & 7)) << 3) + (n & 7);
        smem[addr] = f2b(s[i] * inv);
      }
    }
  }
  __syncthreads();

  // ---- hoist this wave's A-fragments (W rows m = wave*16 + col) ----
  bf16x8 af[8];
  {
    int m = wave * 16 + col;
#pragma unroll
    for (int ks = 0; ks < 8; ++ks) {
      int c = (ks * 4 + quad) ^ (m & 7);
      af[ks] = *(const bf16x8*)(smem + m * 256 + c * 8);
    }
  }
  __syncthreads();                                   // smem now reusable

  // output row addresses for this lane's 4 acc rows
  int prow[4];
#pragma unroll
  for (int r = 0; r < 4; ++r) {
    int m = wave * 16 + quad * 4 + r;
    prow[r] = pb + (h0 + (m >> 3)) * 96 + w0 + (m & 7);
  }

  // staging: thread covers window px = gp*8+i (i<8), ch = cg*8 .. cg*8+7
  const int gp = tid & 31, cg = tid >> 5;
  const int hh = h0 - 4 + (gp >> 1);
  const int wb = w0 - 4 + (gp & 1) * 8;
  const bool vrow = (unsigned)hh < 96u;
  const u16* src[8];
  bool ok[8];
#pragma unroll
  for (int i = 0; i < 8; ++i) {
    int wwi = wb + i;
    ok[i] = vrow && ((unsigned)wwi < 96u);
    src[i] = gphi + (size_t)(pb + hh * 96 + wwi) * 1024 + cg * 8;
  }

  for (int c0 = 0; c0 < 512; c0 += 64) {
    uint4 v[8];
#pragma unroll
    for (int i = 0; i < 8; ++i) {
      uint4 t4 = make_uint4(0, 0, 0, 0);
      if (ok[i]) t4 = *(const uint4*)(src[i] + c0);
      v[i] = t4;
    }
    __syncthreads();                                 // prev chunk consumed
    // 8x8 u16 transpose; write row ch=cg*8+j, px gp*8..+7 (swizzled chunk)
#pragma unroll
    for (int j = 0; j < 8; ++j) {
      int sw = j >> 1;
      u32 x0 = ((const u32*)&v[0])[sw], x1 = ((const u32*)&v[1])[sw];
      u32 x2 = ((const u32*)&v[2])[sw], x3 = ((const u32*)&v[3])[sw];
      u32 x4 = ((const u32*)&v[4])[sw], x5 = ((const u32*)&v[5])[sw];
      u32 x6 = ((const u32*)&v[6])[sw], x7 = ((const u32*)&v[7])[sw];
      uint4 o;
      if (j & 1) {
        o.x = (x0 >> 16) | (x1 & 0xffff0000u);
        o.y = (x2 >> 16) | (x3 & 0xffff0000u);
        o.z = (x4 >> 16) | (x5 & 0xffff0000u);
        o.w = (x6 >> 16) | (x7 & 0xffff0000u);
      } else {
        o.x = (x0 & 0xffffu) | (x1 << 16);
        o.y = (x2 & 0xffffu) | (x3 << 16);
        o.z = (x4 & 0xffffu) | (x5 << 16);
        o.w = (x6 & 0xffffu) | (x7 << 16);
      }
      *(uint4*)(smem + (cg * 8 + j) * 256 + ((gp ^ j) << 3)) = o;
    }
    __syncthreads();

    f32x4 acc[4] = {};
#pragma unroll
    for (int ks = 0; ks < 8; ++ks) {
      bf16x8 bfr[4];
#pragma unroll
      for (int nt = 0; nt < 4; ++nt) {
        int ch = nt * 16 + col;
        int c = (ks * 4 + quad) ^ (ch & 7);
        bfr[nt] = *(const bf16x8*)(smem + ch * 256 + c * 8);
      }
#pragma unroll
      for (int nt = 0; nt < 4; ++nt)
        acc[nt] = __builtin_amdgcn_mfma_f32_16x16x32_bf16(af[ks], bfr[nt],
                                                          acc[nt], 0, 0, 0);
    }
#pragma unroll
    for (int nt = 0; nt < 4; ++nt) {
      int ch = c0 + nt * 16 + col;
#pragma unroll
      for (int r = 0; r < 4; ++r)
        y[(size_t)prow[r] * 512 + ch] = f2b(acc[nt][r]);
    }
  }
}

// ---------------------------------------------------------------------------
extern "C" void kernel_launch(void* const* d_in, const int* in_sizes, int n_in,
                              void* d_out, int out_size, void* d_ws,
                              size_t ws_size, hipStream_t stream) {
  const float* x    = (const float*)d_in[0];
  const float* xref = (const float*)d_in[1];
  const float* w_g  = (const float*)d_in[2];
  const float* b_g  = (const float*)d_in[3];
  const float* w_th = (const float*)d_in[4];
  const float* b_th = (const float*)d_in[5];
  const float* w_ph = (const float*)d_in[6];
  const float* b_ph = (const float*)d_in[7];
  const float* w_o  = (const float*)d_in[8];
  const float* b_o  = (const float*)d_in[9];

  char* ws = (char*)d_ws;
  // big holds x_ref^T (bf16), then x^T, then y — sequential lifetimes.
  u16*   big    = (u16*)(ws);                        // 75,497,472 B
  u16*   gphi   = (u16*)(ws + 75497472);             // 75,497,472 B
  u16*   theta  = (u16*)(ws + 150994944);            // 37,748,736 B
  float* scores = (float*)(ws + 188743680);          // 11,943,936 B
  u16*   wgp    = (u16*)(ws + 200687616);            //  2,097,152 B
  u16*   wth    = (u16*)(ws + 202784768);            //  1,048,576 B
  u16*   wout   = (u16*)(ws + 203833344);            //  1,048,576 B
  // zero page: carved inside `big` past y's 37.75MB live range (48MB offset);
  // zeroed after the last full overwrite of big (x transpose).
  u16*   zpage  = big + 24 * 1024 * 1024;            // 1 KB zeros

  // weights -> bf16 (w_g & w_phi stacked into one [1024][1024] B-operand)
  cvt_pairs<<<1024, 256, 0, stream>>>(w_g, wgp, 262144);
  cvt_pairs<<<1024, 256, 0, stream>>>(w_ph, wgp + 524288, 262144);
  cvt_pairs<<<1024, 256, 0, stream>>>(w_th, wth, 262144);
  cvt_pairs<<<1024, 256, 0, stream>>>(w_o, wout, 262144);

  dim3 tb(32, 8);
  // x_ref -> [p][c] bf16, then g|phi = xref^T x [w_g;w_phi]^T  (N=1024)
  transpose_cvt<<<dim3(288, 16, 4), tb, 0, stream>>>(xref, big);
  gemm256<0><<<dim3(8, 144), 512, 0, stream>>>(big, wgp, 1024, gphi, 1024,
                                               b_g, b_ph, 512, nullptr,
                                               nullptr);
  // x -> [p][c] bf16 (reuses big), then theta (N=512)
  transpose_cvt<<<dim3(288, 16, 4), tb, 0, stream>>>(x, big);
  gemm256<0><<<dim3(4, 144), 512, 0, stream>>>(big, wth, 1024, theta, 512,
                                               b_th, b_th, 512, nullptr,
                                               nullptr);

  zero1k<<<1, 256, 0, stream>>>((u32*)zpage);

  corr_mfma<<<dim3(12, 12, 4), 256, 0, stream>>>(theta, gphi, scores, zpage);
  assemble3<<<dim3(12, 12, 4), 256, 0, stream>>>(scores, gphi, big /* y */);

  // out = x + y x w_out^T + b_out   (fp32, fused residual epilogue)
  gemm256<1><<<dim3(8, 144), 512, 0, stream>>>(big, wout, 512, nullptr, 0,
                                               b_o, b_o, 1024, (float*)d_out,
                                               x);
}

// Round 5
// 676.989 us; speedup vs baseline: 1.2520x; 1.0323x over previous
//
#include <hip/hip_runtime.h>
#include <hip/hip_bf16.h>

typedef unsigned short u16;
typedef unsigned int   u32;
typedef unsigned long long uptr;
typedef short bf16x8 __attribute__((ext_vector_type(8)));
typedef float f32x4  __attribute__((ext_vector_type(4)));

#define PIMG 9216           // 96*96 pixels per image
#define HH 96
#define WW 96
// 256/(512*sqrt(96)) = 0.5/sqrt(96)
#define SCALE 0.05103103630798288f

__device__ __forceinline__ u16 f2b(float f) {          // fp32 -> bf16 RNE
  u32 u = __float_as_uint(f);
  u += 0x7fffu + ((u >> 16) & 1u);
  return (u16)(u >> 16);
}

__device__ __forceinline__ void gl2lds16(const void* g, void* l) {
  __builtin_amdgcn_global_load_lds(
      (const __attribute__((address_space(1))) void*)(uptr)g,
      (__attribute__((address_space(3))) void*)(uptr)l, 16, 0, 0);
}

// ---------------------------------------------------------------------------
// fp32 [C][P] -> bf16 [P][C] transpose+convert (per batch in blockIdx.z)
// ---------------------------------------------------------------------------
__global__ void __launch_bounds__(256)
transpose_cvt(const float* __restrict__ src, u16* __restrict__ dst) {
  __shared__ float tile[64][33];
  const int tx = threadIdx.x, ty = threadIdx.y;      // (32,8)
  const int p0 = blockIdx.x * 32, c0 = blockIdx.y * 64;
  const float* s = src + (size_t)blockIdx.z * 1024 * PIMG;
  u16* d = dst + (size_t)blockIdx.z * PIMG * 1024;
#pragma unroll
  for (int i = 0; i < 8; ++i) {
    int c = ty + i * 8;
    tile[c][tx] = s[(size_t)(c0 + c) * PIMG + p0 + tx];
  }
  __syncthreads();
#pragma unroll
  for (int i = 0; i < 4; ++i) {
    int p = ty + i * 8;
    u32 lo = f2b(tile[2 * tx][p]);
    u32 hi = f2b(tile[2 * tx + 1][p]);
    *(u32*)(d + (size_t)(p0 + p) * 1024 + c0 + 2 * tx) = lo | (hi << 16);
  }
}

// fp32 -> bf16 pairwise convert (weights)
__global__ void __launch_bounds__(256)
cvt_pairs(const float* __restrict__ s, u16* __restrict__ d, int n2) {
  int i = blockIdx.x * blockDim.x + threadIdx.x;
  if (i < n2) {
    float2 v = ((const float2*)s)[i];
    ((u32*)d)[i] = (u32)f2b(v.x) | ((u32)f2b(v.y) << 16);
  }
}

__global__ void zero1k(u32* z) { z[threadIdx.x] = 0; }   // 256 thr -> 1KB zeros

// ---------------------------------------------------------------------------
// GEMM: C[p][o] = sum_c A[p][c] * B[o][c]   (A row-major [M][K], B [N][K])
// 256x128 tile, BK=64, 8 waves (2Mx4N), tri-buffered LDS, counted vmcnt(6),
// raw s_barrier (ONE per K-step), phased MFMA clusters with setprio.
// EPI=1: coalesced fp32 epilogue — acc tile stashed to (dead) staging LDS
// transposed (XOR-swizzled), re-read channel-row-major so x-load/add/store
// are 1KB-contiguous per wave per channel row.
// XCD-aware bijective swizzle (nwg % 8 == 0 for all our grids).
// ---------------------------------------------------------------------------
#define BUFSZ (256 * 64 + 128 * 64)                  // u16 per buffer (48 KB)

template <int EPI>
__global__ void __launch_bounds__(512)
gemm256(const u16* __restrict__ A, const u16* __restrict__ B, int K,
        u16* __restrict__ outb, int ldo,
        const float* __restrict__ bias0, const float* __restrict__ bias1,
        int split, float* __restrict__ outf, const float* __restrict__ xres) {
  __shared__ __attribute__((aligned(16))) u16 lds[3 * BUFSZ];   // 144 KiB

  const int tid = threadIdx.x;
  const int wave = tid >> 6, lane = tid & 63;
  const int quad = lane >> 4, col = lane & 15;
  const int wr = wave >> 2, wc = wave & 3;           // 2 m-halves x 4 n-quads

  const int nbx = gridDim.x;
  const int nwg = nbx * gridDim.y;
  const int id = blockIdx.x + nbx * blockIdx.y;
  const int nid = (id & 7) * (nwg >> 3) + (id >> 3); // bijective XCD swizzle
  const int m0 = (nid / nbx) * 256, n0 = (nid % nbx) * 128;

  f32x4 acc[8][2] = {};

  // staging thread->unit maps (unit = 16B chunk), XOR-swizzled chunk in row
  int arow[4], akc[4];
#pragma unroll
  for (int i = 0; i < 4; ++i) {
    int u = i * 512 + tid;
    arow[i] = u >> 3;
    akc[i] = (u & 7) ^ (arow[i] & 7);
  }
  int brow[2], bkc[2];
#pragma unroll
  for (int i = 0; i < 2; ++i) {
    int u = i * 512 + tid;
    brow[i] = u >> 3;
    bkc[i] = (u & 7) ^ (brow[i] & 7);
  }

  const int NT = K >> 6;

#define STAGE_A(t, i)                                                      \
  gl2lds16(A + (size_t)(m0 + arow[i]) * K + (t) * 64 + akc[i] * 8,         \
           lds + ((t) % 3) * BUFSZ + ((i) * 512 + wave * 64) * 8)
#define STAGE_B(t, i)                                                      \
  gl2lds16(B + (size_t)(n0 + brow[i]) * K + (t) * 64 + bkc[i] * 8,         \
           lds + ((t) % 3) * BUFSZ + 256 * 64 + ((i) * 512 + wave * 64) * 8)

  // prologue: steps 0 and 1 in flight (12 loads/thread-wave)
  STAGE_A(0, 0); STAGE_A(0, 1); STAGE_A(0, 2); STAGE_A(0, 3);
  STAGE_B(0, 0); STAGE_B(0, 1);
  if (NT > 1) {
    STAGE_A(1, 0); STAGE_A(1, 1); STAGE_A(1, 2); STAGE_A(1, 3);
    STAGE_B(1, 0); STAGE_B(1, 1);
  }

  for (int t = 0; t < NT; ++t) {
    if (t + 1 < NT)
      asm volatile("s_waitcnt vmcnt(6)" ::: "memory");
    else
      asm volatile("s_waitcnt vmcnt(0)" ::: "memory");
    asm volatile("s_barrier" ::: "memory");

    const u16* bufA = lds + (t % 3) * BUFSZ;
    const u16* bufB = bufA + 256 * 64;
    const bool pf = (t + 2 < NT);

    bf16x8 bfr[2][2];
#pragma unroll
    for (int nt = 0; nt < 2; ++nt)
#pragma unroll
      for (int ks = 0; ks < 2; ++ks) {
        int row = wc * 32 + nt * 16 + col;
        int pos = (ks * 4 + quad) ^ (row & 7);
        bfr[nt][ks] = *(const bf16x8*)(bufB + row * 64 + pos * 8);
      }

#pragma unroll
    for (int q = 0; q < 4; ++q) {
      bf16x8 af[2][2];
#pragma unroll
      for (int mi = 0; mi < 2; ++mi)
#pragma unroll
        for (int ks = 0; ks < 2; ++ks) {
          int row = wr * 128 + (q * 2 + mi) * 16 + col;
          int pos = (ks * 4 + quad) ^ (row & 7);
          af[mi][ks] = *(const bf16x8*)(bufA + row * 64 + pos * 8);
        }
      if (pf) {
        if (q == 0) { STAGE_A(t + 2, 0); STAGE_A(t + 2, 1); }
        else if (q == 1) { STAGE_A(t + 2, 2); STAGE_A(t + 2, 3); }
        else if (q == 2) { STAGE_B(t + 2, 0); }
        else { STAGE_B(t + 2, 1); }
      }
      __builtin_amdgcn_s_setprio(1);
#pragma unroll
      for (int mi = 0; mi < 2; ++mi)
#pragma unroll
        for (int nt = 0; nt < 2; ++nt)
#pragma unroll
          for (int ks = 0; ks < 2; ++ks)
            acc[q * 2 + mi][nt] = __builtin_amdgcn_mfma_f32_16x16x32_bf16(
                af[mi][ks], bfr[nt][ks], acc[q * 2 + mi][nt], 0, 0, 0);
      __builtin_amdgcn_s_setprio(0);
    }
  }
#undef STAGE_A
#undef STAGE_B

  if (EPI == 0) {
#pragma unroll
    for (int nt = 0; nt < 2; ++nt) {
      int n = n0 + wc * 32 + nt * 16 + col;
      float bv = (n < split) ? bias0[n] : bias1[n - split];
#pragma unroll
      for (int mt = 0; mt < 8; ++mt) {
        int mb = m0 + wr * 128 + mt * 16 + quad * 4;
#pragma unroll
        for (int r = 0; r < 4; ++r)
          outb[(size_t)(mb + r) * ldo + n] = f2b(acc[mt][nt][r] + bv);
      }
    }
  } else {
    // ---- coalesced fp32 epilogue via LDS transpose (staging LDS is dead) --
    __syncthreads();                                 // all buf ds_reads done
    float* ldsF = (float*)lds;                       // [128 ch][256 px], XOR
#pragma unroll
    for (int nt = 0; nt < 2; ++nt) {
      int cl = wc * 32 + nt * 16 + col;              // local channel 0..127
#pragma unroll
      for (int mt = 0; mt < 8; ++mt) {
        int pl = wr * 128 + mt * 16 + quad * 4;      // local pixel, mult of 4
        int ps = pl ^ ((cl & 7) << 2);
        *(f32x4*)(ldsF + cl * 256 + ps) = acc[mt][nt];
      }
    }
    __syncthreads();
    int b = m0 / PIMG;                               // tile never crosses image
    int pbase = m0 - b * PIMG;
    const float* xr = xres + ((size_t)b * 1024 + n0) * PIMG + pbase;
    float* op = outf + ((size_t)b * 1024 + n0) * PIMG + pbase;
    const int pl = lane * 4;
#pragma unroll
    for (int i = 0; i < 16; ++i) {
      int cl = i * 8 + wave;                         // channel row 0..127
      float bv = bias0[n0 + cl];
      int ps = pl ^ ((cl & 7) << 2);
      f32x4 v = *(const f32x4*)(ldsF + cl * 256 + ps);
      const float4 xv = *(const float4*)(xr + (size_t)cl * PIMG + pl);
      float4 o;
      o.x = v[0] + bv + xv.x;
      o.y = v[1] + bv + xv.y;
      o.z = v[2] + bv + xv.z;
      o.w = v[3] + bv + xv.w;
      *(float4*)(op + (size_t)cl * PIMG + pl) = o;
    }
  }
}

// ---------------------------------------------------------------------------
// Correlation via MFMA. Block = 8x8 pixel patch (grid 12x12x4).
// A = theta[64 patch pixels][512], B = phi[16x16 window pixels][512];
// scores[m][n] -> (p, q) with q = (ny-py)*9 + (nx-px) when both in [0,8].
// OOB phi rows are staged from a zero page (score 0, matching the zero-pad
// reference; zeros still participate in softmax downstream).
// ---------------------------------------------------------------------------
__global__ void __launch_bounds__(256)
corr_mfma(const u16* __restrict__ theta, const u16* __restrict__ gphi,
          float* __restrict__ scores, const u16* __restrict__ zpage) {
  __shared__ u16 tlds[64 * 64];                      // 8 KB
  __shared__ u16 plds[256 * 64];                     // 32 KB
  const int tid = threadIdx.x;
  const int wave = tid >> 6, lane = tid & 63;
  const int quad = lane >> 4, col = lane & 15;
  const int h0 = blockIdx.y * 8, w0 = blockIdx.x * 8;
  const int pb = blockIdx.z * PIMG;

  const u16* tsrc[2];
#pragma unroll
  for (int i = 0; i < 2; ++i) {
    int u = i * 256 + tid;
    int row = u >> 3, c = u & 7;
    int p = pb + (h0 + (row >> 3)) * 96 + w0 + (row & 7);
    tsrc[i] = theta + (size_t)p * 512 + ((c ^ (row & 7)) * 8);
  }
  const u16* psrc[8];
#pragma unroll
  for (int i = 0; i < 8; ++i) {
    int u = i * 256 + tid;
    int row = u >> 3, c = u & 7;
    int hh = h0 - 4 + (row >> 4), w2 = w0 - 4 + (row & 15);
    const u16* s = ((unsigned)hh < 96u && (unsigned)w2 < 96u)
        ? gphi + (size_t)(pb + hh * 96 + w2) * 1024 + 512 : zpage;
    psrc[i] = s + ((c ^ (row & 7)) * 8);
  }

  f32x4 acc[4][4] = {};
  for (int k0 = 0; k0 < 512; k0 += 64) {
    __syncthreads();
#pragma unroll
    for (int i = 0; i < 2; ++i)
      gl2lds16(tsrc[i] + k0, tlds + (i * 256 + wave * 64) * 8);
#pragma unroll
    for (int i = 0; i < 8; ++i)
      gl2lds16(psrc[i] + k0, plds + (i * 256 + wave * 64) * 8);
    __syncthreads();
#pragma unroll
    for (int ks = 0; ks < 2; ++ks) {
      bf16x8 af[4], bfr[4];
#pragma unroll
      for (int mt = 0; mt < 4; ++mt) {
        int row = mt * 16 + col;
        int pos = (ks * 4 + quad) ^ (row & 7);
        af[mt] = *(const bf16x8*)(tlds + row * 64 + pos * 8);
      }
#pragma unroll
      for (int nt = 0; nt < 4; ++nt) {
        int row = (wave * 4 + nt) * 16 + col;
        int pos = (ks * 4 + quad) ^ (row & 7);
        bfr[nt] = *(const bf16x8*)(plds + row * 64 + pos * 8);
      }
#pragma unroll
      for (int mt = 0; mt < 4; ++mt)
#pragma unroll
        for (int nt = 0; nt < 4; ++nt)
          acc[mt][nt] = __builtin_amdgcn_mfma_f32_16x16x32_bf16(
              af[mt], bfr[nt], acc[mt][nt], 0, 0, 0);
    }
  }

#pragma unroll
  for (int nt = 0; nt < 4; ++nt) {
    int ny = wave * 4 + nt;                          // window row of this n
#pragma unroll
    for (int mt = 0; mt < 4; ++mt) {
#pragma unroll
      for (int r = 0; r < 4; ++r) {
        int m = mt * 16 + quad * 4 + r;
        int py = m >> 3, pxl = m & 7;
        int a = ny - py, b = col - pxl;
        if ((unsigned)a <= 8u && (unsigned)b <= 8u) {
          int p = pb + (h0 + py) * 96 + w0 + pxl;
          scores[(size_t)p * 81 + a * 9 + b] = acc[mt][nt][r] * SCALE;
        }
      }
    }
  }
}

// ---------------------------------------------------------------------------
// Softmax + assemble via MFMA. Block = 8x8 pixel patch (grid 12x12x4).
// y[64 px][512 ch] = W[64 px][256 window px] x G[256 window px][512 ch].
// ---------------------------------------------------------------------------
__global__ void __launch_bounds__(256)
assemble3(const float* __restrict__ scores, const u16* __restrict__ gphi,
          u16* __restrict__ y) {
  __shared__ u16 smem[64 * 256];                     // 32 KB: W, then G^T
  const int tid = threadIdx.x;
  const int wave = tid >> 6, lane = tid & 63;
  const int quad = lane >> 4, col = lane & 15;
  const int h0 = blockIdx.y * 8, w0 = blockIdx.x * 8;
  const int pb = blockIdx.z * PIMG;

  // ---- zero W ----
  {
    uint4 z4 = make_uint4(0, 0, 0, 0);
#pragma unroll
    for (int i = 0; i < 8; ++i)
      *(uint4*)(smem + (tid * 8 + i) * 8) = z4;
  }
  __syncthreads();

  // ---- softmax (4 lanes per pixel row) + scatter into W ----
  {
    const int m = tid >> 2, part = tid & 3;
    const int py = m >> 3, px = m & 7;
    const float* srow = scores + (size_t)(pb + (h0 + py) * 96 + w0 + px) * 81;
    float s[21];
    float mx = -1e30f;
#pragma unroll
    for (int i = 0; i < 21; ++i) {
      int q = part + 4 * i;
      s[i] = (q < 81) ? srow[q] : -1e30f;
      mx = fmaxf(mx, s[i]);
    }
    mx = fmaxf(mx, __shfl_xor(mx, 1));
    mx = fmaxf(mx, __shfl_xor(mx, 2));
    float sum = 0.f;
#pragma unroll
    for (int i = 0; i < 21; ++i) {
      int q = part + 4 * i;
      float e = (q < 81) ? __expf(s[i] - mx) : 0.f;
      s[i] = e;
      sum += e;
    }
    sum += __shfl_xor(sum, 1);
    sum += __shfl_xor(sum, 2);
    float inv = 1.0f / sum;
#pragma unroll
    for (int i = 0; i < 21; ++i) {
      int q = part + 4 * i;
      if (q < 81) {
        int a = q / 9, b = q - a * 9;
        int n = (py + a) * 16 + px + b;               // window pixel index
        int addr = m * 256 + (((n >> 3) ^ (m & 7)) << 3) + (n & 7);
        smem[addr] = f2b(s[i] * inv);
      }
    }
  }
  __syncthreads();

  // ---- hoist this wave's A-fragments (W rows m = wave*16 + col) ----
  bf16x8 af[8];
  {
    int m = wave * 16 + col;
#pragma unroll
    for (int ks = 0; ks < 8; ++ks) {
      int c = (ks * 4 + quad) ^ (m & 7);
      af[ks] = *(const bf16x8*)(smem + m * 256 + c * 8);
    }
  }
  __syncthreads();                                   // smem now reusable

  // output row addresses for this lane's 4 acc rows
  int prow[4];
#pragma unroll
  for (int r = 0; r < 4; ++r) {
    int m = wave * 16 + quad * 4 + r;
    prow[r] = pb + (h0 + (m >> 3)) * 96 + w0 + (m & 7);
  }

  // staging: thread covers window px = gp*8+i (i<8), ch = cg*8 .. cg*8+7
  const int gp = tid & 31, cg = tid >> 5;
  const int hh = h0 - 4 + (gp >> 1);
  const int wb = w0 - 4 + (gp & 1) * 8;
  const bool vrow = (unsigned)hh < 96u;
  const u16* src[8];
  bool ok[8];
#pragma unroll
  for (int i = 0; i < 8; ++i) {
    int wwi = wb + i;
    ok[i] = vrow && ((unsigned)wwi < 96u);
    src[i] = gphi + (size_t)(pb + hh * 96 + wwi) * 1024 + cg * 8;
  }

  for (int c0 = 0; c0 < 512; c0 += 64) {
    uint4 v[8];
#pragma unroll
    for (int i = 0; i < 8; ++i) {
      uint4 t4 = make_uint4(0, 0, 0, 0);
      if (ok[i]) t4 = *(const uint4*)(src[i] + c0);
      v[i] = t4;
    }
    __syncthreads();                                 // prev chunk consumed
    // 8x8 u16 transpose; write row ch=cg*8+j, px gp*8..+7 (swizzled chunk)
#pragma unroll
    for (int j = 0; j < 8; ++j) {
      int sw = j >> 1;
      u32 x0 = ((const u32*)&v[0])[sw], x1 = ((const u32*)&v[1])[sw];
      u32 x2 = ((const u32*)&v[2])[sw], x3 = ((const u32*)&v[3])[sw];
      u32 x4 = ((const u32*)&v[4])[sw], x5 = ((const u32*)&v[5])[sw];
      u32 x6 = ((const u32*)&v[6])[sw], x7 = ((const u32*)&v[7])[sw];
      uint4 o;
      if (j & 1) {
        o.x = (x0 >> 16) | (x1 & 0xffff0000u);
        o.y = (x2 >> 16) | (x3 & 0xffff0000u);
        o.z = (x4 >> 16) | (x5 & 0xffff0000u);
        o.w = (x6 >> 16) | (x7 & 0xffff0000u);
      } else {
        o.x = (x0 & 0xffffu) | (x1 << 16);
        o.y = (x2 & 0xffffu) | (x3 << 16);
        o.z = (x4 & 0xffffu) | (x5 << 16);
        o.w = (x6 & 0xffffu) | (x7 << 16);
      }
      *(uint4*)(smem + (cg * 8 + j) * 256 + ((gp ^ j) << 3)) = o;
    }
    __syncthreads();

    f32x4 acc[4] = {};
#pragma unroll
    for (int ks = 0; ks < 8; ++ks) {
      bf16x8 bfr[4];
#pragma unroll
      for (int nt = 0; nt < 4; ++nt) {
        int ch = nt * 16 + col;
        int c = (ks * 4 + quad) ^ (ch & 7);
        bfr[nt] = *(const bf16x8*)(smem + ch * 256 + c * 8);
      }
#pragma unroll
      for (int nt = 0; nt < 4; ++nt)
        acc[nt] = __builtin_amdgcn_mfma_f32_16x16x32_bf16(af[ks], bfr[nt],
                                                          acc[nt], 0, 0, 0);
    }
#pragma unroll
    for (int nt = 0; nt < 4; ++nt) {
      int ch = c0 + nt * 16 + col;
#pragma unroll
      for (int r = 0; r < 4; ++r)
        y[(size_t)prow[r] * 512 + ch] = f2b(acc[nt][r]);
    }
  }
}

// ---------------------------------------------------------------------------
extern "C" void kernel_launch(void* const* d_in, const int* in_sizes, int n_in,
                              void* d_out, int out_size, void* d_ws,
                              size_t ws_size, hipStream_t stream) {
  const float* x    = (const float*)d_in[0];
  const float* xref = (const float*)d_in[1];
  const float* w_g  = (const float*)d_in[2];
  const float* b_g  = (const float*)d_in[3];
  const float* w_th = (const float*)d_in[4];
  const float* b_th = (const float*)d_in[5];
  const float* w_ph = (const float*)d_in[6];
  const float* b_ph = (const float*)d_in[7];
  const float* w_o  = (const float*)d_in[8];
  const float* b_o  = (const float*)d_in[9];

  char* ws = (char*)d_ws;
  // big holds x_ref^T (bf16), then x^T, then y — sequential lifetimes.
  u16*   big    = (u16*)(ws);                        // 75,497,472 B
  u16*   gphi   = (u16*)(ws + 75497472);             // 75,497,472 B
  u16*   theta  = (u16*)(ws + 150994944);            // 37,748,736 B
  float* scores = (float*)(ws + 188743680);          // 11,943,936 B
  u16*   wgp    = (u16*)(ws + 200687616);            //  2,097,152 B
  u16*   wth    = (u16*)(ws + 202784768);            //  1,048,576 B
  u16*   wout   = (u16*)(ws + 203833344);            //  1,048,576 B
  // zero page: carved inside `big` past y's 37.75MB live range (48MB offset);
  // zeroed after the last full overwrite of big (x transpose).
  u16*   zpage  = big + 24 * 1024 * 1024;            // 1 KB zeros

  // weights -> bf16 (w_g & w_phi stacked into one [1024][1024] B-operand)
  cvt_pairs<<<1024, 256, 0, stream>>>(w_g, wgp, 262144);
  cvt_pairs<<<1024, 256, 0, stream>>>(w_ph, wgp + 524288, 262144);
  cvt_pairs<<<1024, 256, 0, stream>>>(w_th, wth, 262144);
  cvt_pairs<<<1024, 256, 0, stream>>>(w_o, wout, 262144);

  dim3 tb(32, 8);
  // x_ref -> [p][c] bf16, then g|phi = xref^T x [w_g;w_phi]^T  (N=1024)
  transpose_cvt<<<dim3(288, 16, 4), tb, 0, stream>>>(xref, big);
  gemm256<0><<<dim3(8, 144), 512, 0, stream>>>(big, wgp, 1024, gphi, 1024,
                                               b_g, b_ph, 512, nullptr,
                                               nullptr);
  // x -> [p][c] bf16 (reuses big), then theta (N=512)
  transpose_cvt<<<dim3(288, 16, 4), tb, 0, stream>>>(x, big);
  gemm256<0><<<dim3(4, 144), 512, 0, stream>>>(big, wth, 1024, theta, 512,
                                               b_th, b_th, 512, nullptr,
                                               nullptr);

  zero1k<<<1, 256, 0, stream>>>((u32*)zpage);

  corr_mfma<<<dim3(12, 12, 4), 256, 0, stream>>>(theta, gphi, scores, zpage);
  assemble3<<<dim3(12, 12, 4), 256, 0, stream>>>(scores, gphi, big /* y */);

  // out = x + y x w_out^T + b_out   (fp32, fused residual epilogue)
  gemm256<1><<<dim3(8, 144), 512, 0, stream>>>(big, wout, 512, nullptr, 0,
                                               b_o, b_o, 1024, (float*)d_out,
                                               x);
}